// Round 9
// baseline (401.098 us; speedup 1.0000x reference)
//
#include <hip/hip_runtime.h>
#include <hip/hip_bf16.h>

#define N_NODES 100000
#define N_EDGES 1600000
#define N_FEAT  16
#define HIDDEN  128
#define N_GRAPHS 512
#define CAP     64            // slots per node (mean deg 16, P(>63)~0)
#define NBKT    782           // ceil(100000/128) coarse buckets (dst>>7)
#define BN      128           // nodes per bucket
#define CAPB    2560          // edges per bucket cap (mean 2048, +11 sigma)
#define EPB     4000          // edges per k_part block (400 blocks)

typedef unsigned short ushort_t;
typedef short v8s __attribute__((ext_vector_type(8)));   // 8 bf16 (4 VGPRs)
typedef float v4f __attribute__((ext_vector_type(4)));   // MFMA accumulator

__device__ __forceinline__ ushort_t f2bf(float f) {
    __hip_bfloat16 b = __float2bfloat16(f);
    return *(ushort_t*)&b;
}
__device__ __forceinline__ float bf_lo(unsigned u) {
    union { unsigned i; float f; } c; c.i = u << 16; return c.f;
}
__device__ __forceinline__ float bf_hi(unsigned u) {
    union { unsigned i; float f; } c; c.i = u & 0xffff0000u; return c.f;
}

// ---------------- phase 1: coarse partition by dst>>7 ----------------

__global__ __launch_bounds__(256) void k_part(const int* __restrict__ src,
                                              const int* __restrict__ dst,
                                              int* __restrict__ bcnt,
                                              int2* __restrict__ ebuf) {
    __shared__ int h[NBKT];
    __shared__ int base[NBKT];
    __shared__ int r[NBKT];
    int tid = threadIdx.x;
    int e0 = blockIdx.x * EPB;

    for (int i = tid; i < NBKT; i += 256) { h[i] = 0; r[i] = 0; }
    __syncthreads();

    for (int i = tid; i < EPB; i += 256)
        atomicAdd(&h[dst[e0 + i] >> 7], 1);
    __syncthreads();

    for (int i = tid; i < NBKT; i += 256)
        base[i] = atomicAdd(&bcnt[i], h[i]);
    __syncthreads();

    for (int i = tid; i < EPB; i += 256) {
        int s = src[e0 + i], d = dst[e0 + i];
        int b = d >> 7;
        int pos = base[b] + atomicAdd(&r[b], 1);
        if (pos < CAPB) ebuf[b * CAPB + pos] = (int2){s, d};
    }
}

// ---------------- phase 2: per-bucket LDS ranking -> esrc64 + cnt + dinv ----------------

__global__ __launch_bounds__(256) void k_fill(const int* __restrict__ bcnt,
                                              const int2* __restrict__ ebuf,
                                              int* __restrict__ esrc64,
                                              int* __restrict__ cnt,
                                              float* __restrict__ dinv) {
    __shared__ int lcnt[BN];
    int tid = threadIdx.x;
    int b = blockIdx.x;
    int node0 = b << 7;

    if (tid < BN) lcnt[tid] = 0;
    __syncthreads();

    int nE = bcnt[b]; nE = nE > CAPB ? CAPB : nE;
    const int2* eb = ebuf + b * CAPB;
    for (int i = tid; i < nE; i += 256) {
        int2 e = eb[i];
        int p = atomicAdd(&lcnt[e.y - node0], 1);
        if (p < CAP) esrc64[(e.y << 6) + p] = e.x;
    }
    __syncthreads();

    if (tid < BN) {
        int node = node0 + tid;
        if (node < N_NODES) {
            int c = lcnt[tid];
            cnt[node] = c;
            dinv[node] = rsqrtf((float)c + 1.0f);
        }
    }
}

// ---------------- x' = x * dinv[node] ----------------

__global__ void k_prescale(const float* __restrict__ x, const float* __restrict__ dinv,
                           float* __restrict__ xs) {
    int i = blockIdx.x * 256 + threadIdx.x;   // over N_NODES*N_FEAT
    xs[i] = x[i] * dinv[i >> 4];
}

// ---------------- edge-centric layer-1 aggregation (LDS f32 atomics) ----------------
// agg16[n] = dd[n] * (xs[n] + sum_{e: dst=n} xs[src])

__global__ __launch_bounds__(256) void k_agg1e(const int* __restrict__ bcnt,
                                               const int2* __restrict__ ebuf,
                                               const float* __restrict__ xs,
                                               const float* __restrict__ dinv,
                                               float* __restrict__ agg16) {
    __shared__ float acc[BN][17];   // pad 17 -> spread LDS atomic banks
    int tid = threadIdx.x;
    int b = blockIdx.x;
    int node0 = b << 7;

    for (int i = tid; i < BN * 16; i += 256) {
        int n = i >> 4, f = i & 15;
        int gn = node0 + n;
        acc[n][f] = (gn < N_NODES) ? xs[gn * N_FEAT + f] : 0.0f;
    }
    __syncthreads();

    int nE = bcnt[b]; nE = nE > CAPB ? CAPB : nE;
    const int2* eb = ebuf + b * CAPB;
    int g = tid >> 4;    // edge group 0..15
    int f = tid & 15;    // feature

    int i = g;
    for (; i + 48 < nE; i += 64) {
        int2 e0 = eb[i], e1 = eb[i + 16], e2 = eb[i + 32], e3 = eb[i + 48];
        float v0 = xs[e0.x * N_FEAT + f];
        float v1 = xs[e1.x * N_FEAT + f];
        float v2 = xs[e2.x * N_FEAT + f];
        float v3 = xs[e3.x * N_FEAT + f];
        atomicAdd(&acc[e0.y & (BN - 1)][f], v0);
        atomicAdd(&acc[e1.y & (BN - 1)][f], v1);
        atomicAdd(&acc[e2.y & (BN - 1)][f], v2);
        atomicAdd(&acc[e3.y & (BN - 1)][f], v3);
    }
    for (; i < nE; i += 16) {
        int2 e = eb[i];
        atomicAdd(&acc[e.y & (BN - 1)][f], xs[e.x * N_FEAT + f]);
    }
    __syncthreads();

    for (int q = tid; q < BN * 16; q += 256) {
        int n = q >> 4, ff = q & 15;
        int gn = node0 + n;
        if (gn < N_NODES) agg16[gn * N_FEAT + ff] = acc[n][ff] * dinv[gn];
    }
}

// ---------------- mm1: h1' = bf16(dinv * relu(agg16 @ W1 + b1)) ----------------

#define MM1_NODES 16
__global__ __launch_bounds__(256) void k_mm1b(const float* __restrict__ a,
                                              const float* __restrict__ W1,
                                              const float* __restrict__ b1,
                                              const float* __restrict__ dinv,
                                              ushort_t* __restrict__ out) {
    __shared__ float sw[N_FEAT][HIDDEN];
    __shared__ float sx[MM1_NODES][N_FEAT + 1];
    __shared__ float sd[MM1_NODES];
    int tid = threadIdx.x;
    int n0 = blockIdx.x * MM1_NODES;

    for (int i = tid; i < N_FEAT * HIDDEN; i += 256)
        sw[i >> 7][i & 127] = W1[i];
    if (tid < MM1_NODES * N_FEAT) {
        int n = tid >> 4, k = tid & 15;
        sx[n][k] = a[(n0 + n) * N_FEAT + k];
    }
    if (tid < MM1_NODES) sd[tid] = dinv[n0 + tid];
    __syncthreads();

    int f = tid & 127, half = tid >> 7;
    float bias = b1[f];
    float acc[8] = {0,0,0,0,0,0,0,0};
    #pragma unroll
    for (int k = 0; k < N_FEAT; ++k) {
        float w = sw[k][f];
        #pragma unroll
        for (int i = 0; i < 8; ++i)
            acc[i] += sx[half * 8 + i][k] * w;
    }
    #pragma unroll
    for (int i = 0; i < 8; ++i) {
        int n = half * 8 + i;
        out[(size_t)(n0 + n) * HIDDEN + f] =
            f2bf(sd[n] * fmaxf(acc[i] + bias, 0.0f));
    }
}

// ---------------- layer-2 aggregation: aggb = bf16(dd * (h1'[self] + sum h1'[s])) ----------------

__global__ __launch_bounds__(256) void k_agg2(const int* __restrict__ cnt,
                                              const int* __restrict__ esrc64,
                                              const float* __restrict__ dinv,
                                              const ushort_t* __restrict__ h1,
                                              ushort_t* __restrict__ aggb) {
    int tid = threadIdx.x;
    int sub = tid >> 5;      // 0..7 node within block
    int l32 = tid & 31;      // 8-byte lane within node row
    int node = blockIdx.x * 8 + sub;
    const uint2* h = (const uint2*)h1;
    int deg = cnt[node]; deg = deg > CAP ? CAP : deg;
    int base = node << 6;
    float dd = dinv[node];

    uint2 sv = h[node * 32 + l32];
    float a0 = bf_lo(sv.x), a1 = bf_hi(sv.x), a2 = bf_lo(sv.y), a3 = bf_hi(sv.y);

    int j = 0;
    for (; j + 4 <= deg; j += 4) {
        int s0 = esrc64[base + j],     s1 = esrc64[base + j + 1];
        int s2 = esrc64[base + j + 2], s3 = esrc64[base + j + 3];
        uint2 v0 = h[s0 * 32 + l32];
        uint2 v1 = h[s1 * 32 + l32];
        uint2 v2 = h[s2 * 32 + l32];
        uint2 v3 = h[s3 * 32 + l32];
        a0 += bf_lo(v0.x) + bf_lo(v1.x) + bf_lo(v2.x) + bf_lo(v3.x);
        a1 += bf_hi(v0.x) + bf_hi(v1.x) + bf_hi(v2.x) + bf_hi(v3.x);
        a2 += bf_lo(v0.y) + bf_lo(v1.y) + bf_lo(v2.y) + bf_lo(v3.y);
        a3 += bf_hi(v0.y) + bf_hi(v1.y) + bf_hi(v2.y) + bf_hi(v3.y);
    }
    for (; j < deg; ++j) {
        int s = esrc64[base + j];
        uint2 v = h[s * 32 + l32];
        a0 += bf_lo(v.x); a1 += bf_hi(v.x);
        a2 += bf_lo(v.y); a3 += bf_hi(v.y);
    }
    ushort4 r;
    r.x = f2bf(a0 * dd); r.y = f2bf(a1 * dd);
    r.z = f2bf(a2 * dd); r.w = f2bf(a3 * dd);
    ((ushort4*)aggb)[node * 32 + l32] = r;
}

// ---------------- pack W2 -> bf16 MFMA B-fragment order ----------------

__global__ void k_packB(const float* __restrict__ W2, ushort_t* __restrict__ Bp) {
    int idx = blockIdx.x * 256 + threadIdx.x;   // 0..16383
    int j = idx & 7;
    int lane = (idx >> 3) & 63;
    int nt = (idx >> 9) & 7;
    int kt = idx >> 12;
    int k = kt * 32 + (lane >> 4) * 8 + j;
    int n = nt * 16 + (lane & 15);
    Bp[idx] = f2bf(W2[k * HIDDEN + n]);
}

// ---------------- mm2 via MFMA, fused head ----------------

__global__ __launch_bounds__(256) void k_mm2m(const ushort_t* __restrict__ A,
                                              const ushort_t* __restrict__ Bp,
                                              const float* __restrict__ b2,
                                              const float* __restrict__ Wl,
                                              float* __restrict__ snode) {
    __shared__ ushort_t sB[16384];   // 32 KB packed W2
    int tid = threadIdx.x;
    {
        const uint4* s = (const uint4*)Bp;
        uint4* d = (uint4*)sB;
        #pragma unroll
        for (int j = 0; j < 8; ++j) d[tid + 256 * j] = s[tid + 256 * j];
    }
    __syncthreads();

    int wv = tid >> 6, lane = tid & 63;
    int m = lane & 15, quad = lane >> 4;
    int node0 = blockIdx.x * 64 + wv * 16;
    const ushort_t* arow = A + (size_t)(node0 + m) * HIDDEN;

    v4f acc[8];
    #pragma unroll
    for (int nt = 0; nt < 8; ++nt) acc[nt] = (v4f){0.f, 0.f, 0.f, 0.f};

    #pragma unroll
    for (int kt = 0; kt < 4; ++kt) {
        v8s a = *(const v8s*)(arow + kt * 32 + quad * 8);
        #pragma unroll
        for (int nt = 0; nt < 8; ++nt) {
            v8s b = *(const v8s*)(&sB[((kt * 8 + nt) * 64 + lane) * 8]);
            acc[nt] = __builtin_amdgcn_mfma_f32_16x16x32_bf16(a, b, acc[nt], 0, 0, 0);
        }
    }

    float part[4] = {0, 0, 0, 0};
    #pragma unroll
    for (int nt = 0; nt < 8; ++nt) {
        float bb = b2[nt * 16 + m];
        float wl = Wl[nt * 16 + m];
        #pragma unroll
        for (int reg = 0; reg < 4; ++reg)
            part[reg] += fmaxf(acc[nt][reg] + bb, 0.0f) * wl;
    }
    #pragma unroll
    for (int reg = 0; reg < 4; ++reg) {
        float p = part[reg];
        p += __shfl_xor(p, 1, 64);
        p += __shfl_xor(p, 2, 64);
        p += __shfl_xor(p, 4, 64);
        p += __shfl_xor(p, 8, 64);
        int node = node0 + quad * 4 + reg;
        if (m == 0 && node < N_NODES) snode[node] = p;
    }
}

// ---------------- pooling: out[g] = mean(snode over graph g) + bl ----------------

__global__ __launch_bounds__(256) void k_pool(const float* __restrict__ snode,
                                              const int* __restrict__ batch,
                                              const float* __restrict__ bl,
                                              float* __restrict__ out) {
    int g = blockIdx.x;
    int tid = threadIdx.x;
    __shared__ float sred[4];

    int lo = 0, hi = N_NODES;
    while (lo < hi) { int mid = (lo + hi) >> 1; if (batch[mid] < g) lo = mid + 1; else hi = mid; }
    int start = lo;
    hi = N_NODES;
    while (lo < hi) { int mid = (lo + hi) >> 1; if (batch[mid] < g + 1) lo = mid + 1; else hi = mid; }
    int end = lo;

    float acc = 0.0f;
    for (int n = start + tid; n < end; n += 256) acc += snode[n];

    #pragma unroll
    for (int off = 32; off; off >>= 1) acc += __shfl_down(acc, off, 64);
    int wave = tid >> 6, lane = tid & 63;
    if (lane == 0) sred[wave] = acc;
    __syncthreads();
    if (tid == 0) {
        float s = sred[0] + sred[1] + sred[2] + sred[3];
        float cnt = (float)(end - start);
        out[g] = s / fmaxf(cnt, 1.0f) + bl[0];
    }
}

// ---------------- launch ----------------

extern "C" void kernel_launch(void* const* d_in, const int* in_sizes, int n_in,
                              void* d_out, int out_size, void* d_ws, size_t ws_size,
                              hipStream_t stream) {
    const float* x    = (const float*)d_in[0];
    const int*   src  = (const int*)d_in[1];
    const int*   dst  = src + N_EDGES;
    const int*   batch= (const int*)d_in[2];
    const float* W1   = (const float*)d_in[3];
    const float* b1   = (const float*)d_in[4];
    const float* W2   = (const float*)d_in[5];
    const float* b2   = (const float*)d_in[6];
    const float* Wl   = (const float*)d_in[7];
    const float* bl   = (const float*)d_in[8];
    float* out = (float*)d_out;

    const size_t NH = (size_t)N_NODES * HIDDEN;

    ushort_t* h1   = (ushort_t*)d_ws;              // NH bf16 (25.6 MB)
    ushort_t* aggb = h1 + NH;                      // NH bf16 (25.6 MB)
    int2*  ebuf    = (int2*)aggb;                  // NBKT*CAPB int2 (16.0 MB), dead before aggb
    float* xs      = (float*)(aggb + NH);          // N_NODES*16 fp32 (6.4 MB)
    float* dinv    = xs + (size_t)N_NODES * N_FEAT;// N_NODES
    float* snode   = dinv + N_NODES;               // N_NODES
    int*   cnt     = (int*)(snode + N_NODES);      // N_NODES
    int*   esrc64  = cnt + N_NODES;                // N_NODES*64 (25.6 MB)
    int*   bcnt    = esrc64 + (size_t)N_NODES * CAP;  // NBKT
    ushort_t* Bp   = (ushort_t*)(bcnt + NBKT);     // 16384 (32 KB)
    float* agg16   = (float*)(Bp + 16384);         // N_NODES*16 fp32 (6.4 MB)

    // two-phase build: coarse partition (128-node buckets), per-bucket LDS ranking
    hipMemsetAsync(bcnt, 0, NBKT * sizeof(int), stream);
    k_part<<<N_EDGES / EPB, 256, 0, stream>>>(src, dst, bcnt, ebuf);
    k_fill<<<NBKT, 256, 0, stream>>>(bcnt, ebuf, esrc64, cnt, dinv);

    k_prescale<<<(N_NODES * N_FEAT + 255) / 256, 256, 0, stream>>>(x, dinv, xs);
    k_packB<<<64, 256, 0, stream>>>(W2, Bp);

    // layer 1: edge-centric LDS-atomic aggregation, then mm1 -> h1'
    k_agg1e<<<NBKT, 256, 0, stream>>>(bcnt, ebuf, xs, dinv, agg16);
    k_mm1b<<<(N_NODES + MM1_NODES - 1) / MM1_NODES, 256, 0, stream>>>(agg16, W1, b1, dinv, h1);

    // layer 2: node-centric bf16 gather aggregate -> bf16, MFMA mm2 + fused head
    k_agg2<<<N_NODES / 8, 256, 0, stream>>>(cnt, esrc64, dinv, h1, aggb);
    k_mm2m<<<(N_NODES + 63) / 64, 256, 0, stream>>>(aggb, Bp, b2, Wl, snode);

    // pool + bias
    k_pool<<<N_GRAPHS, 256, 0, stream>>>(snode, batch, bl, out);
}

// Round 10
// 270.109 us; speedup vs baseline: 1.4849x; 1.4849x over previous
//
#include <hip/hip_runtime.h>
#include <hip/hip_bf16.h>

#define N_NODES 100000
#define N_EDGES 1600000
#define N_FEAT  16
#define HIDDEN  128
#define N_GRAPHS 512
#define CAP     64            // slots per node (mean deg 16, P(>63)~0)
#define NBKT    782           // ceil(100000/128) coarse buckets (dst>>7)
#define BN      128           // nodes per bucket
#define CAPB    2560          // edges per bucket cap (mean 2048, +11 sigma)
#define EPB     4000          // edges per k_part block (400 blocks)

typedef unsigned short ushort_t;
typedef short v8s __attribute__((ext_vector_type(8)));   // 8 bf16 (4 VGPRs)
typedef float v4f __attribute__((ext_vector_type(4)));   // MFMA accumulator

__device__ __forceinline__ ushort_t f2bf(float f) {
    __hip_bfloat16 b = __float2bfloat16(f);
    return *(ushort_t*)&b;
}
__device__ __forceinline__ float bfu(ushort_t u) {
    union { unsigned i; float f; } c; c.i = ((unsigned)u) << 16; return c.f;
}
__device__ __forceinline__ float bf_lo(unsigned u) {
    union { unsigned i; float f; } c; c.i = u << 16; return c.f;
}
__device__ __forceinline__ float bf_hi(unsigned u) {
    union { unsigned i; float f; } c; c.i = u & 0xffff0000u; return c.f;
}

// ---------------- phase 1: coarse partition by dst>>7 ----------------

__global__ __launch_bounds__(256) void k_part(const int* __restrict__ src,
                                              const int* __restrict__ dst,
                                              int* __restrict__ bcnt,
                                              int2* __restrict__ ebuf) {
    __shared__ int h[NBKT];
    __shared__ int base[NBKT];
    __shared__ int r[NBKT];
    int tid = threadIdx.x;
    int e0 = blockIdx.x * EPB;

    for (int i = tid; i < NBKT; i += 256) { h[i] = 0; r[i] = 0; }
    __syncthreads();

    for (int i = tid; i < EPB; i += 256)
        atomicAdd(&h[dst[e0 + i] >> 7], 1);
    __syncthreads();

    for (int i = tid; i < NBKT; i += 256)
        base[i] = atomicAdd(&bcnt[i], h[i]);
    __syncthreads();

    for (int i = tid; i < EPB; i += 256) {
        int s = src[e0 + i], d = dst[e0 + i];
        int b = d >> 7;
        int pos = base[b] + atomicAdd(&r[b], 1);
        if (pos < CAPB) ebuf[b * CAPB + pos] = (int2){s, d};
    }
}

// ---------------- phase 2: per-bucket LDS ranking -> esrc64 + cnt + dinv ----------------

__global__ __launch_bounds__(256) void k_fill(const int* __restrict__ bcnt,
                                              const int2* __restrict__ ebuf,
                                              int* __restrict__ esrc64,
                                              int* __restrict__ cnt,
                                              float* __restrict__ dinv) {
    __shared__ int lcnt[BN];
    int tid = threadIdx.x;
    int b = blockIdx.x;
    int node0 = b << 7;

    if (tid < BN) lcnt[tid] = 0;
    __syncthreads();

    int nE = bcnt[b]; nE = nE > CAPB ? CAPB : nE;
    const int2* eb = ebuf + b * CAPB;
    for (int i = tid; i < nE; i += 256) {
        int2 e = eb[i];
        int p = atomicAdd(&lcnt[e.y - node0], 1);
        if (p < CAP) esrc64[(e.y << 6) + p] = e.x;
    }
    __syncthreads();

    if (tid < BN) {
        int node = node0 + tid;
        if (node < N_NODES) {
            int c = lcnt[tid];
            cnt[node] = c;
            dinv[node] = rsqrtf((float)c + 1.0f);
        }
    }
}

// ---------------- xb = bf16(x * dinv[node])  (3.2 MB -> fits per-XCD L2) ----------------

__global__ void k_prescale(const float* __restrict__ x, const float* __restrict__ dinv,
                           ushort_t* __restrict__ xb) {
    int i = blockIdx.x * 256 + threadIdx.x;   // over N_NODES*N_FEAT
    xb[i] = f2bf(x[i] * dinv[i >> 4]);
}

// ---------------- fused layer-1: agg(16-dim bf16 gather) + mm1 + relu -> h1' ----------------
// 1 wave/node: lanes = 4 edge-groups x 16 feats; unroll x4 -> 16 gathers in flight.

__global__ __launch_bounds__(256) void k_agg1f(const int* __restrict__ cnt,
                                               const int* __restrict__ esrc64,
                                               const float* __restrict__ dinv,
                                               const ushort_t* __restrict__ xb,
                                               const float* __restrict__ W1,
                                               const float* __restrict__ b1,
                                               ushort_t* __restrict__ h1) {
    __shared__ float sw[N_FEAT * HIDDEN];   // 8 KB
    __shared__ float sb[HIDDEN];
    int tid = threadIdx.x;
    for (int i = tid; i < N_FEAT * HIDDEN; i += 256) sw[i] = W1[i];
    if (tid < HIDDEN) sb[tid] = b1[tid];
    __syncthreads();

    int wv = tid >> 6, lane = tid & 63;
    int e = lane >> 4, f = lane & 15;
    int node = blockIdx.x * 4 + wv;
    int deg = cnt[node]; deg = deg > CAP ? CAP : deg;
    float dd = dinv[node];
    int base = node << 6;

    float a = 0.0f;
    int j = e;
    for (; j + 12 < deg; j += 16) {
        int sA = esrc64[base + j];
        int sB = esrc64[base + j + 4];
        int sC = esrc64[base + j + 8];
        int sD = esrc64[base + j + 12];
        a += bfu(xb[sA * N_FEAT + f]) + bfu(xb[sB * N_FEAT + f])
           + bfu(xb[sC * N_FEAT + f]) + bfu(xb[sD * N_FEAT + f]);
    }
    for (; j < deg; j += 4) {
        int s = esrc64[base + j];
        a += bfu(xb[s * N_FEAT + f]);
    }
    a += __shfl_xor(a, 16, 64);
    a += __shfl_xor(a, 32, 64);
    a = (a + bfu(xb[node * N_FEAT + f])) * dd;   // + self (x' already has one dinv)

    // mm1: lane covers output cols lane and lane+64
    float c0 = sb[lane], c1 = sb[lane + 64];
    #pragma unroll
    for (int k = 0; k < N_FEAT; ++k) {
        float ak = __shfl(a, k, 64);        // feature k lives on lane k
        c0 += ak * sw[k * HIDDEN + lane];
        c1 += ak * sw[k * HIDDEN + lane + 64];
    }
    size_t rb = (size_t)node * HIDDEN;
    h1[rb + lane]      = f2bf(dd * fmaxf(c0, 0.0f));   // h1' = dinv[node]*relu
    h1[rb + lane + 64] = f2bf(dd * fmaxf(c1, 0.0f));
}

// ---------------- layer-2 aggregation: aggb = bf16(dd * (h1'[self] + sum h1'[s])) ----------------

__global__ __launch_bounds__(256) void k_agg2(const int* __restrict__ cnt,
                                              const int* __restrict__ esrc64,
                                              const float* __restrict__ dinv,
                                              const ushort_t* __restrict__ h1,
                                              ushort_t* __restrict__ aggb) {
    int tid = threadIdx.x;
    int sub = tid >> 5;      // 0..7 node within block
    int l32 = tid & 31;      // 8-byte lane within node row
    int node = blockIdx.x * 8 + sub;
    const uint2* h = (const uint2*)h1;
    int deg = cnt[node]; deg = deg > CAP ? CAP : deg;
    int base = node << 6;
    float dd = dinv[node];

    uint2 sv = h[node * 32 + l32];
    float a0 = bf_lo(sv.x), a1 = bf_hi(sv.x), a2 = bf_lo(sv.y), a3 = bf_hi(sv.y);

    int j = 0;
    for (; j + 4 <= deg; j += 4) {
        int s0 = esrc64[base + j],     s1 = esrc64[base + j + 1];
        int s2 = esrc64[base + j + 2], s3 = esrc64[base + j + 3];
        uint2 v0 = h[s0 * 32 + l32];
        uint2 v1 = h[s1 * 32 + l32];
        uint2 v2 = h[s2 * 32 + l32];
        uint2 v3 = h[s3 * 32 + l32];
        a0 += bf_lo(v0.x) + bf_lo(v1.x) + bf_lo(v2.x) + bf_lo(v3.x);
        a1 += bf_hi(v0.x) + bf_hi(v1.x) + bf_hi(v2.x) + bf_hi(v3.x);
        a2 += bf_lo(v0.y) + bf_lo(v1.y) + bf_lo(v2.y) + bf_lo(v3.y);
        a3 += bf_hi(v0.y) + bf_hi(v1.y) + bf_hi(v2.y) + bf_hi(v3.y);
    }
    for (; j < deg; ++j) {
        int s = esrc64[base + j];
        uint2 v = h[s * 32 + l32];
        a0 += bf_lo(v.x); a1 += bf_hi(v.x);
        a2 += bf_lo(v.y); a3 += bf_hi(v.y);
    }
    ushort4 r;
    r.x = f2bf(a0 * dd); r.y = f2bf(a1 * dd);
    r.z = f2bf(a2 * dd); r.w = f2bf(a3 * dd);
    ((ushort4*)aggb)[node * 32 + l32] = r;
}

// ---------------- pack W2 -> bf16 MFMA B-fragment order ----------------

__global__ void k_packB(const float* __restrict__ W2, ushort_t* __restrict__ Bp) {
    int idx = blockIdx.x * 256 + threadIdx.x;   // 0..16383
    int j = idx & 7;
    int lane = (idx >> 3) & 63;
    int nt = (idx >> 9) & 7;
    int kt = idx >> 12;
    int k = kt * 32 + (lane >> 4) * 8 + j;
    int n = nt * 16 + (lane & 15);
    Bp[idx] = f2bf(W2[k * HIDDEN + n]);
}

// ---------------- mm2 via MFMA, fused head ----------------

__global__ __launch_bounds__(256) void k_mm2m(const ushort_t* __restrict__ A,
                                              const ushort_t* __restrict__ Bp,
                                              const float* __restrict__ b2,
                                              const float* __restrict__ Wl,
                                              float* __restrict__ snode) {
    __shared__ ushort_t sB[16384];   // 32 KB packed W2
    int tid = threadIdx.x;
    {
        const uint4* s = (const uint4*)Bp;
        uint4* d = (uint4*)sB;
        #pragma unroll
        for (int j = 0; j < 8; ++j) d[tid + 256 * j] = s[tid + 256 * j];
    }
    __syncthreads();

    int wv = tid >> 6, lane = tid & 63;
    int m = lane & 15, quad = lane >> 4;
    int node0 = blockIdx.x * 64 + wv * 16;
    const ushort_t* arow = A + (size_t)(node0 + m) * HIDDEN;

    v4f acc[8];
    #pragma unroll
    for (int nt = 0; nt < 8; ++nt) acc[nt] = (v4f){0.f, 0.f, 0.f, 0.f};

    #pragma unroll
    for (int kt = 0; kt < 4; ++kt) {
        v8s a = *(const v8s*)(arow + kt * 32 + quad * 8);
        #pragma unroll
        for (int nt = 0; nt < 8; ++nt) {
            v8s b = *(const v8s*)(&sB[((kt * 8 + nt) * 64 + lane) * 8]);
            acc[nt] = __builtin_amdgcn_mfma_f32_16x16x32_bf16(a, b, acc[nt], 0, 0, 0);
        }
    }

    float part[4] = {0, 0, 0, 0};
    #pragma unroll
    for (int nt = 0; nt < 8; ++nt) {
        float bb = b2[nt * 16 + m];
        float wl = Wl[nt * 16 + m];
        #pragma unroll
        for (int reg = 0; reg < 4; ++reg)
            part[reg] += fmaxf(acc[nt][reg] + bb, 0.0f) * wl;
    }
    #pragma unroll
    for (int reg = 0; reg < 4; ++reg) {
        float p = part[reg];
        p += __shfl_xor(p, 1, 64);
        p += __shfl_xor(p, 2, 64);
        p += __shfl_xor(p, 4, 64);
        p += __shfl_xor(p, 8, 64);
        int node = node0 + quad * 4 + reg;
        if (m == 0 && node < N_NODES) snode[node] = p;
    }
}

// ---------------- pooling: out[g] = mean(snode over graph g) + bl ----------------

__global__ __launch_bounds__(256) void k_pool(const float* __restrict__ snode,
                                              const int* __restrict__ batch,
                                              const float* __restrict__ bl,
                                              float* __restrict__ out) {
    int g = blockIdx.x;
    int tid = threadIdx.x;
    __shared__ float sred[4];

    int lo = 0, hi = N_NODES;
    while (lo < hi) { int mid = (lo + hi) >> 1; if (batch[mid] < g) lo = mid + 1; else hi = mid; }
    int start = lo;
    hi = N_NODES;
    while (lo < hi) { int mid = (lo + hi) >> 1; if (batch[mid] < g + 1) lo = mid + 1; else hi = mid; }
    int end = lo;

    float acc = 0.0f;
    for (int n = start + tid; n < end; n += 256) acc += snode[n];

    #pragma unroll
    for (int off = 32; off; off >>= 1) acc += __shfl_down(acc, off, 64);
    int wave = tid >> 6, lane = tid & 63;
    if (lane == 0) sred[wave] = acc;
    __syncthreads();
    if (tid == 0) {
        float s = sred[0] + sred[1] + sred[2] + sred[3];
        float cnt = (float)(end - start);
        out[g] = s / fmaxf(cnt, 1.0f) + bl[0];
    }
}

// ---------------- launch ----------------

extern "C" void kernel_launch(void* const* d_in, const int* in_sizes, int n_in,
                              void* d_out, int out_size, void* d_ws, size_t ws_size,
                              hipStream_t stream) {
    const float* x    = (const float*)d_in[0];
    const int*   src  = (const int*)d_in[1];
    const int*   dst  = src + N_EDGES;
    const int*   batch= (const int*)d_in[2];
    const float* W1   = (const float*)d_in[3];
    const float* b1   = (const float*)d_in[4];
    const float* W2   = (const float*)d_in[5];
    const float* b2   = (const float*)d_in[6];
    const float* Wl   = (const float*)d_in[7];
    const float* bl   = (const float*)d_in[8];
    float* out = (float*)d_out;

    const size_t NH = (size_t)N_NODES * HIDDEN;

    ushort_t* h1   = (ushort_t*)d_ws;              // NH bf16 (25.6 MB)
    ushort_t* aggb = h1 + NH;                      // NH bf16 (25.6 MB)
    int2*  ebuf    = (int2*)aggb;                  // NBKT*CAPB int2 (16.0 MB), dead before aggb
    ushort_t* xb   = aggb + NH;                    // N_NODES*16 bf16 (3.2 MB)
    float* dinv    = (float*)(xb + (size_t)N_NODES * N_FEAT);  // N_NODES
    float* snode   = dinv + N_NODES;               // N_NODES
    int*   cnt     = (int*)(snode + N_NODES);      // N_NODES
    int*   esrc64  = cnt + N_NODES;                // N_NODES*64 (25.6 MB)
    int*   bcnt    = esrc64 + (size_t)N_NODES * CAP;  // NBKT
    ushort_t* Bp   = (ushort_t*)(bcnt + NBKT);     // 16384 (32 KB)

    // two-phase build: coarse partition (128-node buckets), per-bucket LDS ranking
    hipMemsetAsync(bcnt, 0, NBKT * sizeof(int), stream);
    k_part<<<N_EDGES / EPB, 256, 0, stream>>>(src, dst, bcnt, ebuf);
    k_fill<<<NBKT, 256, 0, stream>>>(bcnt, ebuf, esrc64, cnt, dinv);

    k_prescale<<<(N_NODES * N_FEAT + 255) / 256, 256, 0, stream>>>(x, dinv, xb);
    k_packB<<<64, 256, 0, stream>>>(W2, Bp);

    // layer 1 fused: bf16 gather aggregate(16) + mm1 + relu -> h1'
    k_agg1f<<<N_NODES / 4, 256, 0, stream>>>(cnt, esrc64, dinv, xb, W1, b1, h1);

    // layer 2: node-centric bf16 gather aggregate -> bf16, MFMA mm2 + fused head
    k_agg2<<<N_NODES / 8, 256, 0, stream>>>(cnt, esrc64, dinv, h1, aggb);
    k_mm2m<<<(N_NODES + 63) / 64, 256, 0, stream>>>(aggb, Bp, b2, Wl, snode);

    // pool + bias
    k_pool<<<N_GRAPHS, 256, 0, stream>>>(snode, batch, bl, out);
}

// Round 11
// 243.213 us; speedup vs baseline: 1.6492x; 1.1106x over previous
//
#include <hip/hip_runtime.h>
#include <hip/hip_bf16.h>

#define N_NODES 100000
#define N_EDGES 1600000
#define N_FEAT  16
#define HIDDEN  128
#define N_GRAPHS 512
#define CAP     64            // slots per node (mean deg 16, P(>63)~0)
#define NBKT    782           // ceil(100000/128) coarse buckets (dst>>7)
#define BN      128           // nodes per bucket
#define CAPB    2560          // edges per bucket cap (mean 2048, +11 sigma)
#define EPB     4000          // edges per k_part block (400 blocks)

typedef unsigned short ushort_t;
typedef short v8s __attribute__((ext_vector_type(8)));   // 8 bf16 (4 VGPRs)
typedef float v4f __attribute__((ext_vector_type(4)));   // MFMA accumulator

__device__ __forceinline__ ushort_t f2bf(float f) {
    __hip_bfloat16 b = __float2bfloat16(f);
    return *(ushort_t*)&b;
}
__device__ __forceinline__ float bf_lo(unsigned u) {
    union { unsigned i; float f; } c; c.i = u << 16; return c.f;
}
__device__ __forceinline__ float bf_hi(unsigned u) {
    union { unsigned i; float f; } c; c.i = u & 0xffff0000u; return c.f;
}

// ---------------- phase 1: coarse partition by dst>>7 ----------------

__global__ __launch_bounds__(256) void k_part(const int* __restrict__ src,
                                              const int* __restrict__ dst,
                                              int* __restrict__ bcnt,
                                              int2* __restrict__ ebuf) {
    __shared__ int h[NBKT];
    __shared__ int base[NBKT];
    __shared__ int r[NBKT];
    int tid = threadIdx.x;
    int e0 = blockIdx.x * EPB;

    for (int i = tid; i < NBKT; i += 256) { h[i] = 0; r[i] = 0; }
    __syncthreads();

    for (int i = tid; i < EPB; i += 256)
        atomicAdd(&h[dst[e0 + i] >> 7], 1);
    __syncthreads();

    for (int i = tid; i < NBKT; i += 256)
        base[i] = atomicAdd(&bcnt[i], h[i]);
    __syncthreads();

    for (int i = tid; i < EPB; i += 256) {
        int s = src[e0 + i], d = dst[e0 + i];
        int b = d >> 7;
        int pos = base[b] + atomicAdd(&r[b], 1);
        if (pos < CAPB) ebuf[b * CAPB + pos] = (int2){s, d};
    }
}

// ---------------- phase 2: per-bucket LDS ranking -> esrc64 + cnt + dinv ----------------
// Pads each node's slots to a multiple of 4 with sentinel N_NODES (zero row).

__global__ __launch_bounds__(256) void k_fill(const int* __restrict__ bcnt,
                                              const int2* __restrict__ ebuf,
                                              int* __restrict__ esrc64,
                                              int* __restrict__ cnt,
                                              float* __restrict__ dinv) {
    __shared__ int lcnt[BN];
    int tid = threadIdx.x;
    int b = blockIdx.x;
    int node0 = b << 7;

    if (tid < BN) lcnt[tid] = 0;
    __syncthreads();

    int nE = bcnt[b]; nE = nE > CAPB ? CAPB : nE;
    const int2* eb = ebuf + b * CAPB;
    for (int i = tid; i < nE; i += 256) {
        int2 e = eb[i];
        int p = atomicAdd(&lcnt[e.y - node0], 1);
        if (p < CAP) esrc64[(e.y << 6) + p] = e.x;
    }
    __syncthreads();

    if (tid < BN) {
        int node = node0 + tid;
        if (node < N_NODES) {
            int c = lcnt[tid];
            cnt[node] = c;
            dinv[node] = rsqrtf((float)c + 1.0f);
            int cc = c > CAP ? CAP : c;
            int pad = (cc + 3) & ~3;
            for (int p = cc; p < pad; ++p)
                esrc64[(node << 6) + p] = N_NODES;   // sentinel -> zero row
        }
    }
}

// ---------------- xb = bf16(x * dinv[node]); zero sentinel rows ----------------

__global__ void k_prescale(const float* __restrict__ x, const float* __restrict__ dinv,
                           ushort_t* __restrict__ xb, ushort_t* __restrict__ h1) {
    int i = blockIdx.x * 256 + threadIdx.x;
    if (i < N_NODES * N_FEAT) {
        xb[i] = f2bf(x[i] * dinv[i >> 4]);
    } else if (i < (N_NODES + 1) * N_FEAT) {
        xb[i] = 0;                                     // xb sentinel row
    } else if (i < (N_NODES + 1) * N_FEAT + HIDDEN) {
        h1[(size_t)N_NODES * HIDDEN + (i - (N_NODES + 1) * N_FEAT)] = 0;  // h1 sentinel row
    }
}

// ---------------- fused layer-1: wide-row gather + LDS mm1 -> h1' ----------------
// 8 lanes/node (uint = 2 bf16 feats), 8 nodes/wave, 32 nodes/block.
// Then k_mm1b-style mm1 phase through LDS (no shfl chains).

__global__ __launch_bounds__(256) void k_agg1f(const int* __restrict__ cnt,
                                               const int* __restrict__ esrc64,
                                               const float* __restrict__ dinv,
                                               const ushort_t* __restrict__ xb,
                                               const float* __restrict__ W1,
                                               const float* __restrict__ b1,
                                               ushort_t* __restrict__ h1) {
    __shared__ float sw[N_FEAT * HIDDEN];   // 8 KB
    __shared__ float sx[32][20];            // 16 feats padded to 20 (float4-aligned rows)
    __shared__ float sdd[32];
    int tid = threadIdx.x;
    for (int i = tid; i < N_FEAT * HIDDEN; i += 256) sw[i] = W1[i];

    int wv = tid >> 6;
    int sub = (tid >> 3) & 7;    // node within wave
    int l8 = tid & 7;            // uint (2 feats) within row
    int nl = wv * 8 + sub;       // node local 0..31
    int node = blockIdx.x * 32 + nl;
    const unsigned* xr = (const unsigned*)xb;   // row = 8 uints

    int deg = cnt[node]; deg = deg > CAP ? CAP : deg;
    int deg4 = (deg + 3) & ~3;
    int base = node << 6;
    float dd = dinv[node];

    float a0 = 0.0f, a1 = 0.0f;
    for (int j = 0; j < deg4; j += 4) {
        int4 id4 = *(const int4*)(esrc64 + base + j);   // 16B aligned (base%64==0, j%4==0)
        unsigned u0 = xr[(unsigned)id4.x * 8 + l8];
        unsigned u1 = xr[(unsigned)id4.y * 8 + l8];
        unsigned u2 = xr[(unsigned)id4.z * 8 + l8];
        unsigned u3 = xr[(unsigned)id4.w * 8 + l8];
        a0 += bf_lo(u0) + bf_lo(u1) + bf_lo(u2) + bf_lo(u3);
        a1 += bf_hi(u0) + bf_hi(u1) + bf_hi(u2) + bf_hi(u3);
    }
    unsigned su = xr[(unsigned)node * 8 + l8];
    a0 = (a0 + bf_lo(su)) * dd;
    a1 = (a1 + bf_hi(su)) * dd;

    sx[nl][2 * l8] = a0;
    sx[nl][2 * l8 + 1] = a1;
    if (l8 == 0) sdd[nl] = dd;
    __syncthreads();

    // mm1 phase: thread = (col f, half); 16 nodes per thread
    int f = tid & 127, half = tid >> 7;
    float bias = b1[f];
    float acc[16];
    #pragma unroll
    for (int n = 0; n < 16; ++n) acc[n] = bias;
    #pragma unroll
    for (int k4 = 0; k4 < 4; ++k4) {
        float w0 = sw[(k4 * 4 + 0) * HIDDEN + f];
        float w1 = sw[(k4 * 4 + 1) * HIDDEN + f];
        float w2 = sw[(k4 * 4 + 2) * HIDDEN + f];
        float w3 = sw[(k4 * 4 + 3) * HIDDEN + f];
        #pragma unroll
        for (int n = 0; n < 16; ++n) {
            float4 xv = *(const float4*)(&sx[half * 16 + n][k4 * 4]);  // broadcast read
            acc[n] += xv.x * w0 + xv.y * w1 + xv.z * w2 + xv.w * w3;
        }
    }
    int n0 = blockIdx.x * 32 + half * 16;
    #pragma unroll
    for (int n = 0; n < 16; ++n)
        h1[(size_t)(n0 + n) * HIDDEN + f] =
            f2bf(sdd[half * 16 + n] * fmaxf(acc[n], 0.0f));
}

// ---------------- layer-2 aggregation: uniform deg4 loop, int4 idx loads ----------------

__global__ __launch_bounds__(256) void k_agg2(const int* __restrict__ cnt,
                                              const int* __restrict__ esrc64,
                                              const float* __restrict__ dinv,
                                              const ushort_t* __restrict__ h1,
                                              ushort_t* __restrict__ aggb) {
    int tid = threadIdx.x;
    int sub = tid >> 5;      // 0..7 node within block
    int l32 = tid & 31;      // 8-byte lane within node row
    int node = blockIdx.x * 8 + sub;
    const uint2* h = (const uint2*)h1;
    int deg = cnt[node]; deg = deg > CAP ? CAP : deg;
    int deg4 = (deg + 3) & ~3;
    int base = node << 6;
    float dd = dinv[node];

    uint2 sv = h[node * 32 + l32];
    float a0 = bf_lo(sv.x), a1 = bf_hi(sv.x), a2 = bf_lo(sv.y), a3 = bf_hi(sv.y);

    for (int j = 0; j < deg4; j += 4) {
        int4 id4 = *(const int4*)(esrc64 + base + j);
        uint2 v0 = h[(unsigned)id4.x * 32 + l32];
        uint2 v1 = h[(unsigned)id4.y * 32 + l32];
        uint2 v2 = h[(unsigned)id4.z * 32 + l32];
        uint2 v3 = h[(unsigned)id4.w * 32 + l32];
        a0 += bf_lo(v0.x) + bf_lo(v1.x) + bf_lo(v2.x) + bf_lo(v3.x);
        a1 += bf_hi(v0.x) + bf_hi(v1.x) + bf_hi(v2.x) + bf_hi(v3.x);
        a2 += bf_lo(v0.y) + bf_lo(v1.y) + bf_lo(v2.y) + bf_lo(v3.y);
        a3 += bf_hi(v0.y) + bf_hi(v1.y) + bf_hi(v2.y) + bf_hi(v3.y);
    }
    ushort4 r;
    r.x = f2bf(a0 * dd); r.y = f2bf(a1 * dd);
    r.z = f2bf(a2 * dd); r.w = f2bf(a3 * dd);
    ((ushort4*)aggb)[node * 32 + l32] = r;
}

// ---------------- pack W2 -> bf16 MFMA B-fragment order ----------------

__global__ void k_packB(const float* __restrict__ W2, ushort_t* __restrict__ Bp) {
    int idx = blockIdx.x * 256 + threadIdx.x;   // 0..16383
    int j = idx & 7;
    int lane = (idx >> 3) & 63;
    int nt = (idx >> 9) & 7;
    int kt = idx >> 12;
    int k = kt * 32 + (lane >> 4) * 8 + j;
    int n = nt * 16 + (lane & 15);
    Bp[idx] = f2bf(W2[k * HIDDEN + n]);
}

// ---------------- mm2 via MFMA, fused head ----------------

__global__ __launch_bounds__(256) void k_mm2m(const ushort_t* __restrict__ A,
                                              const ushort_t* __restrict__ Bp,
                                              const float* __restrict__ b2,
                                              const float* __restrict__ Wl,
                                              float* __restrict__ snode) {
    __shared__ ushort_t sB[16384];   // 32 KB packed W2
    int tid = threadIdx.x;
    {
        const uint4* s = (const uint4*)Bp;
        uint4* d = (uint4*)sB;
        #pragma unroll
        for (int j = 0; j < 8; ++j) d[tid + 256 * j] = s[tid + 256 * j];
    }
    __syncthreads();

    int wv = tid >> 6, lane = tid & 63;
    int m = lane & 15, quad = lane >> 4;
    int node0 = blockIdx.x * 64 + wv * 16;
    const ushort_t* arow = A + (size_t)(node0 + m) * HIDDEN;

    v4f acc[8];
    #pragma unroll
    for (int nt = 0; nt < 8; ++nt) acc[nt] = (v4f){0.f, 0.f, 0.f, 0.f};

    #pragma unroll
    for (int kt = 0; kt < 4; ++kt) {
        v8s a = *(const v8s*)(arow + kt * 32 + quad * 8);
        #pragma unroll
        for (int nt = 0; nt < 8; ++nt) {
            v8s b = *(const v8s*)(&sB[((kt * 8 + nt) * 64 + lane) * 8]);
            acc[nt] = __builtin_amdgcn_mfma_f32_16x16x32_bf16(a, b, acc[nt], 0, 0, 0);
        }
    }

    float part[4] = {0, 0, 0, 0};
    #pragma unroll
    for (int nt = 0; nt < 8; ++nt) {
        float bb = b2[nt * 16 + m];
        float wl = Wl[nt * 16 + m];
        #pragma unroll
        for (int reg = 0; reg < 4; ++reg)
            part[reg] += fmaxf(acc[nt][reg] + bb, 0.0f) * wl;
    }
    #pragma unroll
    for (int reg = 0; reg < 4; ++reg) {
        float p = part[reg];
        p += __shfl_xor(p, 1, 64);
        p += __shfl_xor(p, 2, 64);
        p += __shfl_xor(p, 4, 64);
        p += __shfl_xor(p, 8, 64);
        int node = node0 + quad * 4 + reg;
        if (m == 0 && node < N_NODES) snode[node] = p;
    }
}

// ---------------- pooling: out[g] = mean(snode over graph g) + bl ----------------

__global__ __launch_bounds__(256) void k_pool(const float* __restrict__ snode,
                                              const int* __restrict__ batch,
                                              const float* __restrict__ bl,
                                              float* __restrict__ out) {
    int g = blockIdx.x;
    int tid = threadIdx.x;
    __shared__ float sred[4];

    int lo = 0, hi = N_NODES;
    while (lo < hi) { int mid = (lo + hi) >> 1; if (batch[mid] < g) lo = mid + 1; else hi = mid; }
    int start = lo;
    hi = N_NODES;
    while (lo < hi) { int mid = (lo + hi) >> 1; if (batch[mid] < g + 1) lo = mid + 1; else hi = mid; }
    int end = lo;

    float acc = 0.0f;
    for (int n = start + tid; n < end; n += 256) acc += snode[n];

    #pragma unroll
    for (int off = 32; off; off >>= 1) acc += __shfl_down(acc, off, 64);
    int wave = tid >> 6, lane = tid & 63;
    if (lane == 0) sred[wave] = acc;
    __syncthreads();
    if (tid == 0) {
        float s = sred[0] + sred[1] + sred[2] + sred[3];
        float cnt = (float)(end - start);
        out[g] = s / fmaxf(cnt, 1.0f) + bl[0];
    }
}

// ---------------- launch ----------------

extern "C" void kernel_launch(void* const* d_in, const int* in_sizes, int n_in,
                              void* d_out, int out_size, void* d_ws, size_t ws_size,
                              hipStream_t stream) {
    const float* x    = (const float*)d_in[0];
    const int*   src  = (const int*)d_in[1];
    const int*   dst  = src + N_EDGES;
    const int*   batch= (const int*)d_in[2];
    const float* W1   = (const float*)d_in[3];
    const float* b1   = (const float*)d_in[4];
    const float* W2   = (const float*)d_in[5];
    const float* b2   = (const float*)d_in[6];
    const float* Wl   = (const float*)d_in[7];
    const float* bl   = (const float*)d_in[8];
    float* out = (float*)d_out;

    const size_t NH  = (size_t)N_NODES * HIDDEN;
    const size_t NH1 = (size_t)(N_NODES + 1) * HIDDEN;   // +1 sentinel row

    ushort_t* h1   = (ushort_t*)d_ws;              // NH1 bf16 (25.6 MB + 256 B)
    ushort_t* aggb = h1 + NH1;                     // NH bf16 (25.6 MB)
    int2*  ebuf    = (int2*)aggb;                  // NBKT*CAPB int2 (16.0 MB), dead before aggb
    ushort_t* xb   = aggb + NH;                    // (N_NODES+1)*16 bf16 (3.2 MB)
    float* dinv    = (float*)(xb + (size_t)(N_NODES + 1) * N_FEAT);  // N_NODES
    float* snode   = dinv + N_NODES;               // N_NODES
    int*   cnt     = (int*)(snode + N_NODES);      // N_NODES
    int*   esrc64  = cnt + N_NODES;                // N_NODES*64 (25.6 MB)
    int*   bcnt    = esrc64 + (size_t)N_NODES * CAP;  // NBKT
    ushort_t* Bp   = (ushort_t*)(bcnt + NBKT);     // 16384 (32 KB)

    // two-phase build: coarse partition (128-node buckets), per-bucket LDS ranking
    hipMemsetAsync(bcnt, 0, NBKT * sizeof(int), stream);
    k_part<<<N_EDGES / EPB, 256, 0, stream>>>(src, dst, bcnt, ebuf);
    k_fill<<<NBKT, 256, 0, stream>>>(bcnt, ebuf, esrc64, cnt, dinv);

    {
        int total = (N_NODES + 1) * N_FEAT + HIDDEN;
        k_prescale<<<(total + 255) / 256, 256, 0, stream>>>(x, dinv, xb, h1);
    }
    k_packB<<<64, 256, 0, stream>>>(W2, Bp);

    // layer 1 fused: wide-row bf16 gather + LDS mm1 -> h1'
    k_agg1f<<<N_NODES / 32, 256, 0, stream>>>(cnt, esrc64, dinv, xb, W1, b1, h1);

    // layer 2: uniform-loop bf16 gather aggregate -> bf16, MFMA mm2 + fused head
    k_agg2<<<N_NODES / 8, 256, 0, stream>>>(cnt, esrc64, dinv, h1, aggb);
    k_mm2m<<<(N_NODES + 63) / 64, 256, 0, stream>>>(aggb, Bp, b2, Wl, snode);

    // pool + bias
    k_pool<<<N_GRAPHS, 256, 0, stream>>>(snode, batch, bl, out);
}

// Round 12
// 231.893 us; speedup vs baseline: 1.7297x; 1.0488x over previous
//
#include <hip/hip_runtime.h>
#include <hip/hip_bf16.h>

#define N_NODES 100000
#define N_EDGES 1600000
#define N_FEAT  16
#define HIDDEN  128
#define N_GRAPHS 512
#define CAP     64            // slots per node (mean deg 16, P(>63)~0)
#define NBKT    782           // ceil(100000/128) coarse buckets (dst>>7)
#define BN      128           // nodes per bucket
#define CAPB    2560          // edges per bucket cap (mean 2048, +11 sigma)
#define EPB     4000          // edges per k_part block (400 blocks)

typedef unsigned short ushort_t;
typedef short v8s __attribute__((ext_vector_type(8)));   // 8 bf16 (4 VGPRs)
typedef float v4f __attribute__((ext_vector_type(4)));   // MFMA accumulator

__device__ __forceinline__ ushort_t f2bf(float f) {
    __hip_bfloat16 b = __float2bfloat16(f);
    return *(ushort_t*)&b;
}
__device__ __forceinline__ float bf_lo(unsigned u) {
    union { unsigned i; float f; } c; c.i = u << 16; return c.f;
}
__device__ __forceinline__ float bf_hi(unsigned u) {
    union { unsigned i; float f; } c; c.i = u & 0xffff0000u; return c.f;
}

// ---------------- phase 1: coarse partition by dst>>7 ----------------
// Edges register-cached (one read of src/dst); ebuf entry packed:
// v = src | (dst_local << 17)   (src < 2^17, dst_local < 128)

__global__ __launch_bounds__(256) void k_part(const int* __restrict__ src,
                                              const int* __restrict__ dst,
                                              int* __restrict__ bcnt,
                                              int* __restrict__ ebuf) {
    __shared__ int h[NBKT];
    __shared__ int base[NBKT];
    __shared__ int r[NBKT];
    int tid = threadIdx.x;
    int e0 = blockIdx.x * EPB;

    for (int i = tid; i < NBKT; i += 256) { h[i] = 0; r[i] = 0; }
    __syncthreads();

    // EPB=4000: threads 0..159 handle 16 edges, the rest 15
    int nloc = (tid < EPB - 15 * 256) ? 16 : 15;
    int v[16], bb[16];
    #pragma unroll
    for (int k = 0; k < 16; ++k) {
        if (k < nloc) {
            int i = e0 + tid + k * 256;
            int s = src[i], d = dst[i];
            bb[k] = d >> 7;
            v[k] = s | ((d & 127) << 17);
            atomicAdd(&h[bb[k]], 1);
        }
    }
    __syncthreads();

    for (int i = tid; i < NBKT; i += 256)
        base[i] = atomicAdd(&bcnt[i], h[i]);
    __syncthreads();

    #pragma unroll
    for (int k = 0; k < 16; ++k) {
        if (k < nloc) {
            int b = bb[k];
            int pos = base[b] + atomicAdd(&r[b], 1);
            if (pos < CAPB) ebuf[b * CAPB + pos] = v[k];
        }
    }
}

// ---------------- phase 2: per-bucket LDS ranking -> esrc64 + cnt + dinv ----------------
// Pads each node's slots to a multiple of 8 with sentinel N_NODES (zero row).

__global__ __launch_bounds__(256) void k_fill(const int* __restrict__ bcnt,
                                              const int* __restrict__ ebuf,
                                              int* __restrict__ esrc64,
                                              int* __restrict__ cnt,
                                              float* __restrict__ dinv) {
    __shared__ int lcnt[BN];
    int tid = threadIdx.x;
    int b = blockIdx.x;
    int node0 = b << 7;

    if (tid < BN) lcnt[tid] = 0;
    __syncthreads();

    int nE = bcnt[b]; nE = nE > CAPB ? CAPB : nE;
    const int* eb = ebuf + b * CAPB;
    for (int i = tid; i < nE; i += 256) {
        int v = eb[i];
        int dl = v >> 17;
        int p = atomicAdd(&lcnt[dl], 1);
        if (p < CAP) esrc64[((node0 + dl) << 6) + p] = v & 0x1FFFF;
    }
    __syncthreads();

    if (tid < BN) {
        int node = node0 + tid;
        if (node < N_NODES) {
            int c = lcnt[tid];
            cnt[node] = c;
            dinv[node] = rsqrtf((float)c + 1.0f);
            int cc = c > CAP ? CAP : c;
            int pad = (cc + 7) & ~7;
            for (int p = cc; p < pad; ++p)
                esrc64[(node << 6) + p] = N_NODES;   // sentinel -> zero row
        }
    }
}

// ---------------- xb = bf16(x * dinv[node]); zero sentinel rows ----------------

__global__ void k_prescale(const float* __restrict__ x, const float* __restrict__ dinv,
                           ushort_t* __restrict__ xb, ushort_t* __restrict__ h1) {
    int i = blockIdx.x * 256 + threadIdx.x;
    if (i < N_NODES * N_FEAT) {
        xb[i] = f2bf(x[i] * dinv[i >> 4]);
    } else if (i < (N_NODES + 1) * N_FEAT) {
        xb[i] = 0;                                     // xb sentinel row
    } else if (i < (N_NODES + 1) * N_FEAT + HIDDEN) {
        h1[(size_t)N_NODES * HIDDEN + (i - (N_NODES + 1) * N_FEAT)] = 0;  // h1 sentinel row
    }
}

// ---------------- fused layer-1: wide-row gather (unroll 8) + LDS mm1 -> h1' ----------------
// 8 lanes/node (uint = 2 bf16 feats), 8 nodes/wave, 32 nodes/block.

__global__ __launch_bounds__(256) void k_agg1f(const int* __restrict__ cnt,
                                               const int* __restrict__ esrc64,
                                               const float* __restrict__ dinv,
                                               const ushort_t* __restrict__ xb,
                                               const float* __restrict__ W1,
                                               const float* __restrict__ b1,
                                               ushort_t* __restrict__ h1) {
    __shared__ float sw[N_FEAT * HIDDEN];   // 8 KB
    __shared__ float sx[32][20];            // 16 feats padded to 20
    __shared__ float sdd[32];
    int tid = threadIdx.x;
    for (int i = tid; i < N_FEAT * HIDDEN; i += 256) sw[i] = W1[i];

    int wv = tid >> 6;
    int sub = (tid >> 3) & 7;    // node within wave
    int l8 = tid & 7;            // uint (2 feats) within row
    int nl = wv * 8 + sub;       // node local 0..31
    int node = blockIdx.x * 32 + nl;
    const unsigned* xr = (const unsigned*)xb;   // row = 8 uints

    int deg = cnt[node]; deg = deg > CAP ? CAP : deg;
    int deg8 = (deg + 7) & ~7;
    int base = node << 6;
    float dd = dinv[node];

    float a0 = 0.0f, a1 = 0.0f;
    for (int j = 0; j < deg8; j += 8) {
        int4 ia = *(const int4*)(esrc64 + base + j);
        int4 ib = *(const int4*)(esrc64 + base + j + 4);
        unsigned u0 = xr[(unsigned)ia.x * 8 + l8];
        unsigned u1 = xr[(unsigned)ia.y * 8 + l8];
        unsigned u2 = xr[(unsigned)ia.z * 8 + l8];
        unsigned u3 = xr[(unsigned)ia.w * 8 + l8];
        unsigned u4 = xr[(unsigned)ib.x * 8 + l8];
        unsigned u5 = xr[(unsigned)ib.y * 8 + l8];
        unsigned u6 = xr[(unsigned)ib.z * 8 + l8];
        unsigned u7 = xr[(unsigned)ib.w * 8 + l8];
        a0 += bf_lo(u0) + bf_lo(u1) + bf_lo(u2) + bf_lo(u3)
            + bf_lo(u4) + bf_lo(u5) + bf_lo(u6) + bf_lo(u7);
        a1 += bf_hi(u0) + bf_hi(u1) + bf_hi(u2) + bf_hi(u3)
            + bf_hi(u4) + bf_hi(u5) + bf_hi(u6) + bf_hi(u7);
    }
    unsigned su = xr[(unsigned)node * 8 + l8];
    a0 = (a0 + bf_lo(su)) * dd;
    a1 = (a1 + bf_hi(su)) * dd;

    sx[nl][2 * l8] = a0;
    sx[nl][2 * l8 + 1] = a1;
    if (l8 == 0) sdd[nl] = dd;
    __syncthreads();

    // mm1 phase: thread = (col f, half); 16 nodes per thread
    int f = tid & 127, half = tid >> 7;
    float bias = b1[f];
    float acc[16];
    #pragma unroll
    for (int n = 0; n < 16; ++n) acc[n] = bias;
    #pragma unroll
    for (int k4 = 0; k4 < 4; ++k4) {
        float w0 = sw[(k4 * 4 + 0) * HIDDEN + f];
        float w1 = sw[(k4 * 4 + 1) * HIDDEN + f];
        float w2 = sw[(k4 * 4 + 2) * HIDDEN + f];
        float w3 = sw[(k4 * 4 + 3) * HIDDEN + f];
        #pragma unroll
        for (int n = 0; n < 16; ++n) {
            float4 xv = *(const float4*)(&sx[half * 16 + n][k4 * 4]);  // broadcast read
            acc[n] += xv.x * w0 + xv.y * w1 + xv.z * w2 + xv.w * w3;
        }
    }
    int n0 = blockIdx.x * 32 + half * 16;
    #pragma unroll
    for (int n = 0; n < 16; ++n)
        h1[(size_t)(n0 + n) * HIDDEN + f] =
            f2bf(sdd[half * 16 + n] * fmaxf(acc[n], 0.0f));
}

// ---------------- layer-2 aggregation: uniform deg8 loop, 8 gathers in flight ----------------

__global__ __launch_bounds__(256) void k_agg2(const int* __restrict__ cnt,
                                              const int* __restrict__ esrc64,
                                              const float* __restrict__ dinv,
                                              const ushort_t* __restrict__ h1,
                                              ushort_t* __restrict__ aggb) {
    int tid = threadIdx.x;
    int sub = tid >> 5;      // 0..7 node within block
    int l32 = tid & 31;      // 8-byte lane within node row
    int node = blockIdx.x * 8 + sub;
    const uint2* h = (const uint2*)h1;
    int deg = cnt[node]; deg = deg > CAP ? CAP : deg;
    int deg8 = (deg + 7) & ~7;
    int base = node << 6;
    float dd = dinv[node];

    uint2 sv = h[node * 32 + l32];
    float a0 = bf_lo(sv.x), a1 = bf_hi(sv.x), a2 = bf_lo(sv.y), a3 = bf_hi(sv.y);

    for (int j = 0; j < deg8; j += 8) {
        int4 ia = *(const int4*)(esrc64 + base + j);
        int4 ib = *(const int4*)(esrc64 + base + j + 4);
        uint2 v0 = h[(unsigned)ia.x * 32 + l32];
        uint2 v1 = h[(unsigned)ia.y * 32 + l32];
        uint2 v2 = h[(unsigned)ia.z * 32 + l32];
        uint2 v3 = h[(unsigned)ia.w * 32 + l32];
        uint2 v4 = h[(unsigned)ib.x * 32 + l32];
        uint2 v5 = h[(unsigned)ib.y * 32 + l32];
        uint2 v6 = h[(unsigned)ib.z * 32 + l32];
        uint2 v7 = h[(unsigned)ib.w * 32 + l32];
        a0 += bf_lo(v0.x) + bf_lo(v1.x) + bf_lo(v2.x) + bf_lo(v3.x)
            + bf_lo(v4.x) + bf_lo(v5.x) + bf_lo(v6.x) + bf_lo(v7.x);
        a1 += bf_hi(v0.x) + bf_hi(v1.x) + bf_hi(v2.x) + bf_hi(v3.x)
            + bf_hi(v4.x) + bf_hi(v5.x) + bf_hi(v6.x) + bf_hi(v7.x);
        a2 += bf_lo(v0.y) + bf_lo(v1.y) + bf_lo(v2.y) + bf_lo(v3.y)
            + bf_lo(v4.y) + bf_lo(v5.y) + bf_lo(v6.y) + bf_lo(v7.y);
        a3 += bf_hi(v0.y) + bf_hi(v1.y) + bf_hi(v2.y) + bf_hi(v3.y)
            + bf_hi(v4.y) + bf_hi(v5.y) + bf_hi(v6.y) + bf_hi(v7.y);
    }
    ushort4 r;
    r.x = f2bf(a0 * dd); r.y = f2bf(a1 * dd);
    r.z = f2bf(a2 * dd); r.w = f2bf(a3 * dd);
    ((ushort4*)aggb)[node * 32 + l32] = r;
}

// ---------------- pack W2 -> bf16 MFMA B-fragment order ----------------

__global__ void k_packB(const float* __restrict__ W2, ushort_t* __restrict__ Bp) {
    int idx = blockIdx.x * 256 + threadIdx.x;   // 0..16383
    int j = idx & 7;
    int lane = (idx >> 3) & 63;
    int nt = (idx >> 9) & 7;
    int kt = idx >> 12;
    int k = kt * 32 + (lane >> 4) * 8 + j;
    int n = nt * 16 + (lane & 15);
    Bp[idx] = f2bf(W2[k * HIDDEN + n]);
}

// ---------------- mm2 via MFMA, fused head ----------------

__global__ __launch_bounds__(256) void k_mm2m(const ushort_t* __restrict__ A,
                                              const ushort_t* __restrict__ Bp,
                                              const float* __restrict__ b2,
                                              const float* __restrict__ Wl,
                                              float* __restrict__ snode) {
    __shared__ ushort_t sB[16384];   // 32 KB packed W2
    int tid = threadIdx.x;
    {
        const uint4* s = (const uint4*)Bp;
        uint4* d = (uint4*)sB;
        #pragma unroll
        for (int j = 0; j < 8; ++j) d[tid + 256 * j] = s[tid + 256 * j];
    }
    __syncthreads();

    int wv = tid >> 6, lane = tid & 63;
    int m = lane & 15, quad = lane >> 4;
    int node0 = blockIdx.x * 64 + wv * 16;
    const ushort_t* arow = A + (size_t)(node0 + m) * HIDDEN;

    v4f acc[8];
    #pragma unroll
    for (int nt = 0; nt < 8; ++nt) acc[nt] = (v4f){0.f, 0.f, 0.f, 0.f};

    #pragma unroll
    for (int kt = 0; kt < 4; ++kt) {
        v8s a = *(const v8s*)(arow + kt * 32 + quad * 8);
        #pragma unroll
        for (int nt = 0; nt < 8; ++nt) {
            v8s b = *(const v8s*)(&sB[((kt * 8 + nt) * 64 + lane) * 8]);
            acc[nt] = __builtin_amdgcn_mfma_f32_16x16x32_bf16(a, b, acc[nt], 0, 0, 0);
        }
    }

    float part[4] = {0, 0, 0, 0};
    #pragma unroll
    for (int nt = 0; nt < 8; ++nt) {
        float bb = b2[nt * 16 + m];
        float wl = Wl[nt * 16 + m];
        #pragma unroll
        for (int reg = 0; reg < 4; ++reg)
            part[reg] += fmaxf(acc[nt][reg] + bb, 0.0f) * wl;
    }
    #pragma unroll
    for (int reg = 0; reg < 4; ++reg) {
        float p = part[reg];
        p += __shfl_xor(p, 1, 64);
        p += __shfl_xor(p, 2, 64);
        p += __shfl_xor(p, 4, 64);
        p += __shfl_xor(p, 8, 64);
        int node = node0 + quad * 4 + reg;
        if (m == 0 && node < N_NODES) snode[node] = p;
    }
}

// ---------------- pooling: out[g] = mean(snode over graph g) + bl ----------------

__global__ __launch_bounds__(256) void k_pool(const float* __restrict__ snode,
                                              const int* __restrict__ batch,
                                              const float* __restrict__ bl,
                                              float* __restrict__ out) {
    int g = blockIdx.x;
    int tid = threadIdx.x;
    __shared__ float sred[4];

    int lo = 0, hi = N_NODES;
    while (lo < hi) { int mid = (lo + hi) >> 1; if (batch[mid] < g) lo = mid + 1; else hi = mid; }
    int start = lo;
    hi = N_NODES;
    while (lo < hi) { int mid = (lo + hi) >> 1; if (batch[mid] < g + 1) lo = mid + 1; else hi = mid; }
    int end = lo;

    float acc = 0.0f;
    for (int n = start + tid; n < end; n += 256) acc += snode[n];

    #pragma unroll
    for (int off = 32; off; off >>= 1) acc += __shfl_down(acc, off, 64);
    int wave = tid >> 6, lane = tid & 63;
    if (lane == 0) sred[wave] = acc;
    __syncthreads();
    if (tid == 0) {
        float s = sred[0] + sred[1] + sred[2] + sred[3];
        float cnt = (float)(end - start);
        out[g] = s / fmaxf(cnt, 1.0f) + bl[0];
    }
}

// ---------------- launch ----------------

extern "C" void kernel_launch(void* const* d_in, const int* in_sizes, int n_in,
                              void* d_out, int out_size, void* d_ws, size_t ws_size,
                              hipStream_t stream) {
    const float* x    = (const float*)d_in[0];
    const int*   src  = (const int*)d_in[1];
    const int*   dst  = src + N_EDGES;
    const int*   batch= (const int*)d_in[2];
    const float* W1   = (const float*)d_in[3];
    const float* b1   = (const float*)d_in[4];
    const float* W2   = (const float*)d_in[5];
    const float* b2   = (const float*)d_in[6];
    const float* Wl   = (const float*)d_in[7];
    const float* bl   = (const float*)d_in[8];
    float* out = (float*)d_out;

    const size_t NH  = (size_t)N_NODES * HIDDEN;
    const size_t NH1 = (size_t)(N_NODES + 1) * HIDDEN;   // +1 sentinel row

    ushort_t* h1   = (ushort_t*)d_ws;              // NH1 bf16 (25.6 MB + 256 B)
    ushort_t* aggb = h1 + NH1;                     // NH bf16 (25.6 MB)
    int*   ebuf    = (int*)aggb;                   // NBKT*CAPB int (8.0 MB), dead before aggb
    ushort_t* xb   = aggb + NH;                    // (N_NODES+1)*16 bf16 (3.2 MB)
    float* dinv    = (float*)(xb + (size_t)(N_NODES + 1) * N_FEAT);  // N_NODES
    float* snode   = dinv + N_NODES;               // N_NODES
    int*   cnt     = (int*)(snode + N_NODES);      // N_NODES
    int*   esrc64  = cnt + N_NODES;                // N_NODES*64 (25.6 MB)
    int*   bcnt    = esrc64 + (size_t)N_NODES * CAP;  // NBKT
    ushort_t* Bp   = (ushort_t*)(bcnt + NBKT);     // 16384 (32 KB)

    // two-phase build: coarse partition (128-node buckets), per-bucket LDS ranking
    hipMemsetAsync(bcnt, 0, NBKT * sizeof(int), stream);
    k_part<<<N_EDGES / EPB, 256, 0, stream>>>(src, dst, bcnt, ebuf);
    k_fill<<<NBKT, 256, 0, stream>>>(bcnt, ebuf, esrc64, cnt, dinv);

    {
        int total = (N_NODES + 1) * N_FEAT + HIDDEN;
        k_prescale<<<(total + 255) / 256, 256, 0, stream>>>(x, dinv, xb, h1);
    }
    k_packB<<<64, 256, 0, stream>>>(W2, Bp);

    // layer 1 fused: wide-row bf16 gather + LDS mm1 -> h1'
    k_agg1f<<<N_NODES / 32, 256, 0, stream>>>(cnt, esrc64, dinv, xb, W1, b1, h1);

    // layer 2: uniform-loop bf16 gather aggregate -> bf16, MFMA mm2 + fused head
    k_agg2<<<N_NODES / 8, 256, 0, stream>>>(cnt, esrc64, dinv, h1, aggb);
    k_mm2m<<<(N_NODES + 63) / 64, 256, 0, stream>>>(aggb, Bp, b2, Wl, snode);

    // pool + bias
    k_pool<<<N_GRAPHS, 256, 0, stream>>>(snode, batch, bl, out);
}

// Round 13
// 227.928 us; speedup vs baseline: 1.7598x; 1.0174x over previous
//
#include <hip/hip_runtime.h>
#include <hip/hip_bf16.h>

#define N_NODES 100000
#define N_EDGES 1600000
#define N_FEAT  16
#define HIDDEN  128
#define N_GRAPHS 512
#define CAP     64            // slots per node (mean deg 16, P(>63)~0)
#define NBKT    782           // ceil(100000/128) coarse buckets (dst>>7)
#define BN      128           // nodes per bucket
#define CAPB    2560          // edges per bucket cap (mean 2048, +11 sigma)
#define EPB     4000          // edges per k_part block (400 blocks)

typedef unsigned short ushort_t;
typedef short v8s __attribute__((ext_vector_type(8)));   // 8 bf16 (4 VGPRs)
typedef float v4f __attribute__((ext_vector_type(4)));   // MFMA accumulator

__device__ __forceinline__ ushort_t f2bf(float f) {
    __hip_bfloat16 b = __float2bfloat16(f);
    return *(ushort_t*)&b;
}
__device__ __forceinline__ float bf_lo(unsigned u) {
    union { unsigned i; float f; } c; c.i = u << 16; return c.f;
}
__device__ __forceinline__ float bf_hi(unsigned u) {
    union { unsigned i; float f; } c; c.i = u & 0xffff0000u; return c.f;
}

// ---------------- phase 1: coarse partition by dst>>7 (+ packB tail blocks) ----------------
// ebuf entry packed: v = src | (dst_local << 17)

__global__ __launch_bounds__(256) void k_part(const int* __restrict__ src,
                                              const int* __restrict__ dst,
                                              int* __restrict__ bcnt,
                                              int* __restrict__ ebuf,
                                              const float* __restrict__ W2,
                                              ushort_t* __restrict__ Bp) {
    int tid = threadIdx.x;

    if (blockIdx.x >= N_EDGES / EPB) {
        // packB: W2 -> bf16 MFMA B-fragment order
        int idx = (blockIdx.x - N_EDGES / EPB) * 256 + tid;   // 0..16383
        int j = idx & 7;
        int lane = (idx >> 3) & 63;
        int nt = (idx >> 9) & 7;
        int kt = idx >> 12;
        int k = kt * 32 + (lane >> 4) * 8 + j;
        int n = nt * 16 + (lane & 15);
        Bp[idx] = f2bf(W2[k * HIDDEN + n]);
        return;
    }

    __shared__ int h[NBKT];
    __shared__ int base[NBKT];
    __shared__ int r[NBKT];
    int e0 = blockIdx.x * EPB;

    for (int i = tid; i < NBKT; i += 256) { h[i] = 0; r[i] = 0; }
    __syncthreads();

    // EPB=4000: threads 0..159 handle 16 edges, the rest 15
    int nloc = (tid < EPB - 15 * 256) ? 16 : 15;
    int v[16], bb[16];
    #pragma unroll
    for (int k = 0; k < 16; ++k) {
        if (k < nloc) {
            int i = e0 + tid + k * 256;
            int s = src[i], d = dst[i];
            bb[k] = d >> 7;
            v[k] = s | ((d & 127) << 17);
            atomicAdd(&h[bb[k]], 1);
        }
    }
    __syncthreads();

    for (int i = tid; i < NBKT; i += 256)
        base[i] = atomicAdd(&bcnt[i], h[i]);
    __syncthreads();

    #pragma unroll
    for (int k = 0; k < 16; ++k) {
        if (k < nloc) {
            int b = bb[k];
            int pos = base[b] + atomicAdd(&r[b], 1);
            if (pos < CAPB) ebuf[b * CAPB + pos] = v[k];
        }
    }
}

// ---------------- phase 2: per-bucket LDS ranking + fused prescale ----------------
// esrc64 slots padded to multiple of 8 with sentinel N_NODES (zero row).
// Also: xb = bf16(x * dinv) for this bucket's nodes; block 0 zeroes sentinel rows.

__global__ __launch_bounds__(256) void k_fill(const int* __restrict__ bcnt,
                                              const int* __restrict__ ebuf,
                                              const float* __restrict__ x,
                                              int* __restrict__ esrc64,
                                              int* __restrict__ cnt,
                                              float* __restrict__ dinv,
                                              ushort_t* __restrict__ xb,
                                              ushort_t* __restrict__ h1) {
    __shared__ int lcnt[BN];
    int tid = threadIdx.x;
    int b = blockIdx.x;
    int node0 = b << 7;

    if (tid < BN) lcnt[tid] = 0;
    __syncthreads();

    int nE = bcnt[b]; nE = nE > CAPB ? CAPB : nE;
    const int* eb = ebuf + b * CAPB;
    for (int i = tid; i < nE; i += 256) {
        int v = eb[i];
        int dl = v >> 17;
        int p = atomicAdd(&lcnt[dl], 1);
        if (p < CAP) esrc64[((node0 + dl) << 6) + p] = v & 0x1FFFF;
    }
    __syncthreads();

    if (tid < BN) {
        int node = node0 + tid;
        if (node < N_NODES) {
            int c = lcnt[tid];
            cnt[node] = c;
            dinv[node] = rsqrtf((float)c + 1.0f);
            int cc = c > CAP ? CAP : c;
            int pad = (cc + 7) & ~7;
            for (int p = cc; p < pad; ++p)
                esrc64[(node << 6) + p] = N_NODES;   // sentinel -> zero row
        }
    }

    // fused prescale for this bucket's nodes (lcnt is final)
    for (int i = tid; i < BN * N_FEAT; i += 256) {
        int nl = i >> 4;
        int node = node0 + nl;
        if (node < N_NODES) {
            float di = rsqrtf((float)lcnt[nl] + 1.0f);
            xb[node * N_FEAT + (i & 15)] = f2bf(x[node * N_FEAT + (i & 15)] * di);
        }
    }

    if (b == 0) {
        if (tid < N_FEAT) xb[N_NODES * N_FEAT + tid] = 0;                 // xb sentinel row
        if (tid < HIDDEN) h1[(size_t)N_NODES * HIDDEN + tid] = 0;         // h1 sentinel row
    }
}

// ---------------- fused layer-1: wide-row gather (unroll 8) + LDS mm1 -> h1' ----------------

__global__ __launch_bounds__(256) void k_agg1f(const int* __restrict__ cnt,
                                               const int* __restrict__ esrc64,
                                               const float* __restrict__ dinv,
                                               const ushort_t* __restrict__ xb,
                                               const float* __restrict__ W1,
                                               const float* __restrict__ b1,
                                               ushort_t* __restrict__ h1) {
    __shared__ float sw[N_FEAT * HIDDEN];   // 8 KB
    __shared__ float sx[32][20];            // 16 feats padded to 20
    __shared__ float sdd[32];
    int tid = threadIdx.x;
    for (int i = tid; i < N_FEAT * HIDDEN; i += 256) sw[i] = W1[i];

    int wv = tid >> 6;
    int sub = (tid >> 3) & 7;    // node within wave
    int l8 = tid & 7;            // uint (2 feats) within row
    int nl = wv * 8 + sub;       // node local 0..31
    int node = blockIdx.x * 32 + nl;
    const unsigned* xr = (const unsigned*)xb;   // row = 8 uints

    int deg = cnt[node]; deg = deg > CAP ? CAP : deg;
    int deg8 = (deg + 7) & ~7;
    int base = node << 6;
    float dd = dinv[node];

    float a0 = 0.0f, a1 = 0.0f;
    for (int j = 0; j < deg8; j += 8) {
        int4 ia = *(const int4*)(esrc64 + base + j);
        int4 ib = *(const int4*)(esrc64 + base + j + 4);
        unsigned u0 = xr[(unsigned)ia.x * 8 + l8];
        unsigned u1 = xr[(unsigned)ia.y * 8 + l8];
        unsigned u2 = xr[(unsigned)ia.z * 8 + l8];
        unsigned u3 = xr[(unsigned)ia.w * 8 + l8];
        unsigned u4 = xr[(unsigned)ib.x * 8 + l8];
        unsigned u5 = xr[(unsigned)ib.y * 8 + l8];
        unsigned u6 = xr[(unsigned)ib.z * 8 + l8];
        unsigned u7 = xr[(unsigned)ib.w * 8 + l8];
        a0 += bf_lo(u0) + bf_lo(u1) + bf_lo(u2) + bf_lo(u3)
            + bf_lo(u4) + bf_lo(u5) + bf_lo(u6) + bf_lo(u7);
        a1 += bf_hi(u0) + bf_hi(u1) + bf_hi(u2) + bf_hi(u3)
            + bf_hi(u4) + bf_hi(u5) + bf_hi(u6) + bf_hi(u7);
    }
    unsigned su = xr[(unsigned)node * 8 + l8];
    a0 = (a0 + bf_lo(su)) * dd;
    a1 = (a1 + bf_hi(su)) * dd;

    sx[nl][2 * l8] = a0;
    sx[nl][2 * l8 + 1] = a1;
    if (l8 == 0) sdd[nl] = dd;
    __syncthreads();

    int f = tid & 127, half = tid >> 7;
    float bias = b1[f];
    float acc[16];
    #pragma unroll
    for (int n = 0; n < 16; ++n) acc[n] = bias;
    #pragma unroll
    for (int k4 = 0; k4 < 4; ++k4) {
        float w0 = sw[(k4 * 4 + 0) * HIDDEN + f];
        float w1 = sw[(k4 * 4 + 1) * HIDDEN + f];
        float w2 = sw[(k4 * 4 + 2) * HIDDEN + f];
        float w3 = sw[(k4 * 4 + 3) * HIDDEN + f];
        #pragma unroll
        for (int n = 0; n < 16; ++n) {
            float4 xv = *(const float4*)(&sx[half * 16 + n][k4 * 4]);
            acc[n] += xv.x * w0 + xv.y * w1 + xv.z * w2 + xv.w * w3;
        }
    }
    int n0 = blockIdx.x * 32 + half * 16;
    #pragma unroll
    for (int n = 0; n < 16; ++n)
        h1[(size_t)(n0 + n) * HIDDEN + f] =
            f2bf(sdd[half * 16 + n] * fmaxf(acc[n], 0.0f));
}

// ---------------- fused layer-2: gather-aggregate -> LDS -> MFMA mm2 + head ----------------
// Block = 64 nodes, 4 waves. Phase 1: wave wv aggregates nodes wv*16..+15
// (2 nodes per wave at a time, 32 lanes x uint2 per node, unroll 8) into LDS
// tile sA (pad-132 rows). Phase 2: MFMA with A from LDS, B from global (L2).

__global__ __launch_bounds__(256) void k_l2(const int* __restrict__ cnt,
                                            const int* __restrict__ esrc64,
                                            const float* __restrict__ dinv,
                                            const ushort_t* __restrict__ h1,
                                            const ushort_t* __restrict__ Bp,
                                            const float* __restrict__ b2,
                                            const float* __restrict__ Wl,
                                            float* __restrict__ snode) {
    __shared__ ushort_t sA[64 * 132];   // 16.9 KB
    int tid = threadIdx.x;
    int wv = tid >> 6, lane = tid & 63;
    int half = lane >> 5, l32 = lane & 31;
    int node0 = blockIdx.x * 64;
    const uint2* h = (const uint2*)h1;

    for (int p = 0; p < 8; ++p) {
        int nl = wv * 16 + p * 2 + half;
        int node = node0 + nl;
        bool valid = node < N_NODES;
        int deg = valid ? cnt[node] : 0; deg = deg > CAP ? CAP : deg;
        int deg8 = (deg + 7) & ~7;
        int base = node << 6;
        float dd = valid ? dinv[node] : 0.0f;
        uint2 sv = valid ? h[node * 32 + l32] : (uint2){0u, 0u};
        float a0 = bf_lo(sv.x), a1 = bf_hi(sv.x), a2 = bf_lo(sv.y), a3 = bf_hi(sv.y);

        for (int j = 0; j < deg8; j += 8) {
            int4 ia = *(const int4*)(esrc64 + base + j);
            int4 ib = *(const int4*)(esrc64 + base + j + 4);
            uint2 v0 = h[(unsigned)ia.x * 32 + l32];
            uint2 v1 = h[(unsigned)ia.y * 32 + l32];
            uint2 v2 = h[(unsigned)ia.z * 32 + l32];
            uint2 v3 = h[(unsigned)ia.w * 32 + l32];
            uint2 v4 = h[(unsigned)ib.x * 32 + l32];
            uint2 v5 = h[(unsigned)ib.y * 32 + l32];
            uint2 v6 = h[(unsigned)ib.z * 32 + l32];
            uint2 v7 = h[(unsigned)ib.w * 32 + l32];
            a0 += bf_lo(v0.x) + bf_lo(v1.x) + bf_lo(v2.x) + bf_lo(v3.x)
                + bf_lo(v4.x) + bf_lo(v5.x) + bf_lo(v6.x) + bf_lo(v7.x);
            a1 += bf_hi(v0.x) + bf_hi(v1.x) + bf_hi(v2.x) + bf_hi(v3.x)
                + bf_hi(v4.x) + bf_hi(v5.x) + bf_hi(v6.x) + bf_hi(v7.x);
            a2 += bf_lo(v0.y) + bf_lo(v1.y) + bf_lo(v2.y) + bf_lo(v3.y)
                + bf_lo(v4.y) + bf_lo(v5.y) + bf_lo(v6.y) + bf_lo(v7.y);
            a3 += bf_hi(v0.y) + bf_hi(v1.y) + bf_hi(v2.y) + bf_hi(v3.y)
                + bf_hi(v4.y) + bf_hi(v5.y) + bf_hi(v6.y) + bf_hi(v7.y);
        }
        ushort4 r;
        r.x = f2bf(a0 * dd); r.y = f2bf(a1 * dd);
        r.z = f2bf(a2 * dd); r.w = f2bf(a3 * dd);
        *(ushort4*)(&sA[nl * 132 + l32 * 4]) = r;
    }
    __syncthreads();

    // phase 2: MFMA. wave wv handles rows wv*16..+15 (the ones it wrote).
    int m = lane & 15, quad = lane >> 4;
    const ushort_t* arow = &sA[(wv * 16 + m) * 132];

    v4f acc[8];
    #pragma unroll
    for (int nt = 0; nt < 8; ++nt) acc[nt] = (v4f){0.f, 0.f, 0.f, 0.f};

    #pragma unroll
    for (int kt = 0; kt < 4; ++kt) {
        union { v8s v; ushort4 q[2]; } au;
        au.q[0] = *(const ushort4*)(arow + kt * 32 + quad * 8);
        au.q[1] = *(const ushort4*)(arow + kt * 32 + quad * 8 + 4);
        #pragma unroll
        for (int nt = 0; nt < 8; ++nt) {
            v8s b = *(const v8s*)(Bp + ((kt * 8 + nt) * 64 + lane) * 8);
            acc[nt] = __builtin_amdgcn_mfma_f32_16x16x32_bf16(au.v, b, acc[nt], 0, 0, 0);
        }
    }

    float part[4] = {0, 0, 0, 0};
    #pragma unroll
    for (int nt = 0; nt < 8; ++nt) {
        float bb = b2[nt * 16 + m];
        float wl = Wl[nt * 16 + m];
        #pragma unroll
        for (int reg = 0; reg < 4; ++reg)
            part[reg] += fmaxf(acc[nt][reg] + bb, 0.0f) * wl;
    }
    int node0b = node0 + wv * 16;
    #pragma unroll
    for (int reg = 0; reg < 4; ++reg) {
        float p = part[reg];
        p += __shfl_xor(p, 1, 64);
        p += __shfl_xor(p, 2, 64);
        p += __shfl_xor(p, 4, 64);
        p += __shfl_xor(p, 8, 64);
        int node = node0b + quad * 4 + reg;
        if (m == 0 && node < N_NODES) snode[node] = p;
    }
}

// ---------------- pooling: out[g] = mean(snode over graph g) + bl ----------------

__global__ __launch_bounds__(256) void k_pool(const float* __restrict__ snode,
                                              const int* __restrict__ batch,
                                              const float* __restrict__ bl,
                                              float* __restrict__ out) {
    int g = blockIdx.x;
    int tid = threadIdx.x;
    __shared__ float sred[4];

    int lo = 0, hi = N_NODES;
    while (lo < hi) { int mid = (lo + hi) >> 1; if (batch[mid] < g) lo = mid + 1; else hi = mid; }
    int start = lo;
    hi = N_NODES;
    while (lo < hi) { int mid = (lo + hi) >> 1; if (batch[mid] < g + 1) lo = mid + 1; else hi = mid; }
    int end = lo;

    float acc = 0.0f;
    for (int n = start + tid; n < end; n += 256) acc += snode[n];

    #pragma unroll
    for (int off = 32; off; off >>= 1) acc += __shfl_down(acc, off, 64);
    int wave = tid >> 6, lane = tid & 63;
    if (lane == 0) sred[wave] = acc;
    __syncthreads();
    if (tid == 0) {
        float s = sred[0] + sred[1] + sred[2] + sred[3];
        float cnt = (float)(end - start);
        out[g] = s / fmaxf(cnt, 1.0f) + bl[0];
    }
}

// ---------------- launch ----------------

extern "C" void kernel_launch(void* const* d_in, const int* in_sizes, int n_in,
                              void* d_out, int out_size, void* d_ws, size_t ws_size,
                              hipStream_t stream) {
    const float* x    = (const float*)d_in[0];
    const int*   src  = (const int*)d_in[1];
    const int*   dst  = src + N_EDGES;
    const int*   batch= (const int*)d_in[2];
    const float* W1   = (const float*)d_in[3];
    const float* b1   = (const float*)d_in[4];
    const float* W2   = (const float*)d_in[5];
    const float* b2   = (const float*)d_in[6];
    const float* Wl   = (const float*)d_in[7];
    const float* bl   = (const float*)d_in[8];
    float* out = (float*)d_out;

    // byte-offset workspace layout, 256 B aligned chunks
    char* w = (char*)d_ws;
    size_t off = 0;
    auto alloc = [&](size_t bytes) { char* p = w + off; off = (off + bytes + 255) & ~(size_t)255; return p; };

    ushort_t* h1   = (ushort_t*)alloc((size_t)(N_NODES + 1) * HIDDEN * 2);   // 25.6 MB (+sentinel)
    int*   ebuf    = (int*)alloc((size_t)NBKT * CAPB * 4);                    // 8.0 MB
    ushort_t* xb   = (ushort_t*)alloc((size_t)(N_NODES + 1) * N_FEAT * 2);   // 3.2 MB (+sentinel)
    float* dinv    = (float*)alloc(N_NODES * 4);
    float* snode   = (float*)alloc(N_NODES * 4);
    int*   cnt     = (int*)alloc(N_NODES * 4);
    int*   esrc64  = (int*)alloc((size_t)N_NODES * CAP * 4);                  // 25.6 MB
    ushort_t* Bp   = (ushort_t*)alloc(16384 * 2);                             // 32 KB (16B-aligned)
    int*   bcnt    = (int*)alloc(NBKT * 4);

    // build: memset bcnt, partition (+packB tail), per-bucket rank (+prescale+sentinels)
    hipMemsetAsync(bcnt, 0, NBKT * sizeof(int), stream);
    k_part<<<N_EDGES / EPB + 64, 256, 0, stream>>>(src, dst, bcnt, ebuf, W2, Bp);
    k_fill<<<NBKT, 256, 0, stream>>>(bcnt, ebuf, x, esrc64, cnt, dinv, xb, h1);

    // layer 1 fused: wide-row bf16 gather + LDS mm1 -> h1'
    k_agg1f<<<N_NODES / 32, 256, 0, stream>>>(cnt, esrc64, dinv, xb, W1, b1, h1);

    // layer 2 fused: gather aggregate -> LDS -> MFMA mm2 + head dot
    k_l2<<<(N_NODES + 63) / 64, 256, 0, stream>>>(cnt, esrc64, dinv, h1, Bp, b2, Wl, snode);

    // pool + bias
    k_pool<<<N_GRAPHS, 256, 0, stream>>>(snode, batch, bl, out);
}

// Round 14
// 225.087 us; speedup vs baseline: 1.7820x; 1.0126x over previous
//
#include <hip/hip_runtime.h>
#include <hip/hip_bf16.h>

#define N_NODES 100000
#define N_EDGES 1600000
#define N_FEAT  16
#define HIDDEN  128
#define N_GRAPHS 512
#define CAP     64            // slots per node (mean deg 16, P(>63)~0)
#define NBKT    782           // ceil(100000/128) coarse buckets (dst>>7)
#define BN      128           // nodes per bucket
#define CAPB    2560          // edges per bucket cap (mean 2048, +11 sigma)
#define EPB     4000          // edges per k_part block (400 blocks)

typedef unsigned short ushort_t;
typedef short v8s __attribute__((ext_vector_type(8)));   // 8 bf16 (4 VGPRs)
typedef float v4f __attribute__((ext_vector_type(4)));   // MFMA accumulator

__device__ __forceinline__ ushort_t f2bf(float f) {
    __hip_bfloat16 b = __float2bfloat16(f);
    return *(ushort_t*)&b;
}
__device__ __forceinline__ float bf_lo(unsigned u) {
    union { unsigned i; float f; } c; c.i = u << 16; return c.f;
}
__device__ __forceinline__ float bf_hi(unsigned u) {
    union { unsigned i; float f; } c; c.i = u & 0xffff0000u; return c.f;
}

// ---------------- phase 1: coarse partition by dst>>7 (+ packB tail blocks) ----------------
// ebuf entry packed: v = src | (dst_local << 17)

__global__ __launch_bounds__(256) void k_part(const int* __restrict__ src,
                                              const int* __restrict__ dst,
                                              int* __restrict__ bcnt,
                                              int* __restrict__ ebuf,
                                              const float* __restrict__ W2,
                                              ushort_t* __restrict__ Bp) {
    int tid = threadIdx.x;

    if (blockIdx.x >= N_EDGES / EPB) {
        // packB: W2 -> bf16 MFMA B-fragment order
        int idx = (blockIdx.x - N_EDGES / EPB) * 256 + tid;   // 0..16383
        int j = idx & 7;
        int lane = (idx >> 3) & 63;
        int nt = (idx >> 9) & 7;
        int kt = idx >> 12;
        int k = kt * 32 + (lane >> 4) * 8 + j;
        int n = nt * 16 + (lane & 15);
        Bp[idx] = f2bf(W2[k * HIDDEN + n]);
        return;
    }

    __shared__ int h[NBKT];
    __shared__ int base[NBKT];
    __shared__ int r[NBKT];
    int e0 = blockIdx.x * EPB;

    for (int i = tid; i < NBKT; i += 256) { h[i] = 0; r[i] = 0; }
    __syncthreads();

    // EPB=4000: threads 0..159 handle 16 edges, the rest 15
    int nloc = (tid < EPB - 15 * 256) ? 16 : 15;
    int v[16], bb[16];
    #pragma unroll
    for (int k = 0; k < 16; ++k) {
        if (k < nloc) {
            int i = e0 + tid + k * 256;
            int s = src[i], d = dst[i];
            bb[k] = d >> 7;
            v[k] = s | ((d & 127) << 17);
            atomicAdd(&h[bb[k]], 1);
        }
    }
    __syncthreads();

    for (int i = tid; i < NBKT; i += 256)
        base[i] = atomicAdd(&bcnt[i], h[i]);
    __syncthreads();

    #pragma unroll
    for (int k = 0; k < 16; ++k) {
        if (k < nloc) {
            int b = bb[k];
            int pos = base[b] + atomicAdd(&r[b], 1);
            if (pos < CAPB) ebuf[b * CAPB + pos] = v[k];
        }
    }
}

// ---------------- phase 2: per-bucket LDS ranking + fused prescale ----------------

__global__ __launch_bounds__(256) void k_fill(const int* __restrict__ bcnt,
                                              const int* __restrict__ ebuf,
                                              const float* __restrict__ x,
                                              int* __restrict__ esrc64,
                                              int* __restrict__ cnt,
                                              float* __restrict__ dinv,
                                              ushort_t* __restrict__ xb,
                                              ushort_t* __restrict__ h1) {
    __shared__ int lcnt[BN];
    int tid = threadIdx.x;
    int b = blockIdx.x;
    int node0 = b << 7;

    if (tid < BN) lcnt[tid] = 0;
    __syncthreads();

    int nE = bcnt[b]; nE = nE > CAPB ? CAPB : nE;
    const int* eb = ebuf + b * CAPB;
    for (int i = tid; i < nE; i += 256) {
        int v = eb[i];
        int dl = v >> 17;
        int p = atomicAdd(&lcnt[dl], 1);
        if (p < CAP) esrc64[((node0 + dl) << 6) + p] = v & 0x1FFFF;
    }
    __syncthreads();

    if (tid < BN) {
        int node = node0 + tid;
        if (node < N_NODES) {
            int c = lcnt[tid];
            cnt[node] = c;
            dinv[node] = rsqrtf((float)c + 1.0f);
            int cc = c > CAP ? CAP : c;
            int pad = (cc + 7) & ~7;
            for (int p = cc; p < pad; ++p)
                esrc64[(node << 6) + p] = N_NODES;   // sentinel -> zero row
        }
    }

    for (int i = tid; i < BN * N_FEAT; i += 256) {
        int nl = i >> 4;
        int node = node0 + nl;
        if (node < N_NODES) {
            float di = rsqrtf((float)lcnt[nl] + 1.0f);
            xb[node * N_FEAT + (i & 15)] = f2bf(x[node * N_FEAT + (i & 15)] * di);
        }
    }

    if (b == 0) {
        if (tid < N_FEAT) xb[N_NODES * N_FEAT + tid] = 0;                 // xb sentinel row
        if (tid < HIDDEN) h1[(size_t)N_NODES * HIDDEN + tid] = 0;         // h1 sentinel row
    }
}

// ---------------- fused layer-1: wide-row gather (unroll 8) + LDS mm1 -> h1' ----------------

__global__ __launch_bounds__(256) void k_agg1f(const int* __restrict__ cnt,
                                               const int* __restrict__ esrc64,
                                               const float* __restrict__ dinv,
                                               const ushort_t* __restrict__ xb,
                                               const float* __restrict__ W1,
                                               const float* __restrict__ b1,
                                               ushort_t* __restrict__ h1) {
    __shared__ float sw[N_FEAT * HIDDEN];   // 8 KB
    __shared__ float sx[32][20];            // 16 feats padded to 20
    __shared__ float sdd[32];
    int tid = threadIdx.x;
    for (int i = tid; i < N_FEAT * HIDDEN; i += 256) sw[i] = W1[i];

    int wv = tid >> 6;
    int sub = (tid >> 3) & 7;    // node within wave
    int l8 = tid & 7;            // uint (2 feats) within row
    int nl = wv * 8 + sub;       // node local 0..31
    int node = blockIdx.x * 32 + nl;
    const unsigned* xr = (const unsigned*)xb;   // row = 8 uints

    int deg = cnt[node]; deg = deg > CAP ? CAP : deg;
    int deg8 = (deg + 7) & ~7;
    int base = node << 6;
    float dd = dinv[node];

    float a0 = 0.0f, a1 = 0.0f;
    for (int j = 0; j < deg8; j += 8) {
        int4 ia = *(const int4*)(esrc64 + base + j);
        int4 ib = *(const int4*)(esrc64 + base + j + 4);
        unsigned u0 = xr[(unsigned)ia.x * 8 + l8];
        unsigned u1 = xr[(unsigned)ia.y * 8 + l8];
        unsigned u2 = xr[(unsigned)ia.z * 8 + l8];
        unsigned u3 = xr[(unsigned)ia.w * 8 + l8];
        unsigned u4 = xr[(unsigned)ib.x * 8 + l8];
        unsigned u5 = xr[(unsigned)ib.y * 8 + l8];
        unsigned u6 = xr[(unsigned)ib.z * 8 + l8];
        unsigned u7 = xr[(unsigned)ib.w * 8 + l8];
        a0 += bf_lo(u0) + bf_lo(u1) + bf_lo(u2) + bf_lo(u3)
            + bf_lo(u4) + bf_lo(u5) + bf_lo(u6) + bf_lo(u7);
        a1 += bf_hi(u0) + bf_hi(u1) + bf_hi(u2) + bf_hi(u3)
            + bf_hi(u4) + bf_hi(u5) + bf_hi(u6) + bf_hi(u7);
    }
    unsigned su = xr[(unsigned)node * 8 + l8];
    a0 = (a0 + bf_lo(su)) * dd;
    a1 = (a1 + bf_hi(su)) * dd;

    sx[nl][2 * l8] = a0;
    sx[nl][2 * l8 + 1] = a1;
    if (l8 == 0) sdd[nl] = dd;
    __syncthreads();

    int f = tid & 127, half = tid >> 7;
    float bias = b1[f];
    float acc[16];
    #pragma unroll
    for (int n = 0; n < 16; ++n) acc[n] = bias;
    #pragma unroll
    for (int k4 = 0; k4 < 4; ++k4) {
        float w0 = sw[(k4 * 4 + 0) * HIDDEN + f];
        float w1 = sw[(k4 * 4 + 1) * HIDDEN + f];
        float w2 = sw[(k4 * 4 + 2) * HIDDEN + f];
        float w3 = sw[(k4 * 4 + 3) * HIDDEN + f];
        #pragma unroll
        for (int n = 0; n < 16; ++n) {
            float4 xv = *(const float4*)(&sx[half * 16 + n][k4 * 4]);
            acc[n] += xv.x * w0 + xv.y * w1 + xv.z * w2 + xv.w * w3;
        }
    }
    int n0 = blockIdx.x * 32 + half * 16;
    #pragma unroll
    for (int n = 0; n < 16; ++n)
        h1[(size_t)(n0 + n) * HIDDEN + f] =
            f2bf(sdd[half * 16 + n] * fmaxf(acc[n], 0.0f));
}

// ---------------- fused layer-2: gather -> LDS -> MFMA mm2 + head ----------------
// Block = 128 threads = 2 waves = 32 nodes; 8.4 KB LDS (occupancy-first shape).
// Wave wv gathers nodes wv*16..+15 into its private LDS slice, then MFMAs them.

__global__ __launch_bounds__(128) void k_l2(const int* __restrict__ cnt,
                                            const int* __restrict__ esrc64,
                                            const float* __restrict__ dinv,
                                            const ushort_t* __restrict__ h1,
                                            const ushort_t* __restrict__ Bp,
                                            const float* __restrict__ b2,
                                            const float* __restrict__ Wl,
                                            float* __restrict__ snode) {
    __shared__ ushort_t sA[32 * 132];   // 8.4 KB
    int tid = threadIdx.x;
    int wv = tid >> 6, lane = tid & 63;
    int half = lane >> 5, l32 = lane & 31;
    int node0 = blockIdx.x * 32;
    const uint2* h = (const uint2*)h1;

    for (int p = 0; p < 8; ++p) {
        int nl = wv * 16 + p * 2 + half;
        int node = node0 + nl;
        int deg = cnt[node]; deg = deg > CAP ? CAP : deg;
        int deg8 = (deg + 7) & ~7;
        int base = node << 6;
        float dd = dinv[node];
        uint2 sv = h[node * 32 + l32];
        float a0 = bf_lo(sv.x), a1 = bf_hi(sv.x), a2 = bf_lo(sv.y), a3 = bf_hi(sv.y);

        for (int j = 0; j < deg8; j += 8) {
            int4 ia = *(const int4*)(esrc64 + base + j);
            int4 ib = *(const int4*)(esrc64 + base + j + 4);
            uint2 v0 = h[(unsigned)ia.x * 32 + l32];
            uint2 v1 = h[(unsigned)ia.y * 32 + l32];
            uint2 v2 = h[(unsigned)ia.z * 32 + l32];
            uint2 v3 = h[(unsigned)ia.w * 32 + l32];
            uint2 v4 = h[(unsigned)ib.x * 32 + l32];
            uint2 v5 = h[(unsigned)ib.y * 32 + l32];
            uint2 v6 = h[(unsigned)ib.z * 32 + l32];
            uint2 v7 = h[(unsigned)ib.w * 32 + l32];
            a0 += bf_lo(v0.x) + bf_lo(v1.x) + bf_lo(v2.x) + bf_lo(v3.x)
                + bf_lo(v4.x) + bf_lo(v5.x) + bf_lo(v6.x) + bf_lo(v7.x);
            a1 += bf_hi(v0.x) + bf_hi(v1.x) + bf_hi(v2.x) + bf_hi(v3.x)
                + bf_hi(v4.x) + bf_hi(v5.x) + bf_hi(v6.x) + bf_hi(v7.x);
            a2 += bf_lo(v0.y) + bf_lo(v1.y) + bf_lo(v2.y) + bf_lo(v3.y)
                + bf_lo(v4.y) + bf_lo(v5.y) + bf_lo(v6.y) + bf_lo(v7.y);
            a3 += bf_hi(v0.y) + bf_hi(v1.y) + bf_hi(v2.y) + bf_hi(v3.y)
                + bf_hi(v4.y) + bf_hi(v5.y) + bf_hi(v6.y) + bf_hi(v7.y);
        }
        ushort4 r;
        r.x = f2bf(a0 * dd); r.y = f2bf(a1 * dd);
        r.z = f2bf(a2 * dd); r.w = f2bf(a3 * dd);
        *(ushort4*)(&sA[nl * 132 + l32 * 4]) = r;
    }
    __syncthreads();   // only 2 waves -> minimal coupling

    // phase 2: MFMA. wave wv handles rows wv*16..+15 (the ones it wrote).
    int m = lane & 15, quad = lane >> 4;
    const ushort_t* arow = &sA[(wv * 16 + m) * 132];

    v4f acc[8];
    #pragma unroll
    for (int nt = 0; nt < 8; ++nt) acc[nt] = (v4f){0.f, 0.f, 0.f, 0.f};

    #pragma unroll
    for (int kt = 0; kt < 4; ++kt) {
        union { v8s v; ushort4 q[2]; } au;
        au.q[0] = *(const ushort4*)(arow + kt * 32 + quad * 8);
        au.q[1] = *(const ushort4*)(arow + kt * 32 + quad * 8 + 4);
        #pragma unroll
        for (int nt = 0; nt < 8; ++nt) {
            v8s b = *(const v8s*)(Bp + ((kt * 8 + nt) * 64 + lane) * 8);
            acc[nt] = __builtin_amdgcn_mfma_f32_16x16x32_bf16(au.v, b, acc[nt], 0, 0, 0);
        }
    }

    float part[4] = {0, 0, 0, 0};
    #pragma unroll
    for (int nt = 0; nt < 8; ++nt) {
        float bb = b2[nt * 16 + m];
        float wl = Wl[nt * 16 + m];
        #pragma unroll
        for (int reg = 0; reg < 4; ++reg)
            part[reg] += fmaxf(acc[nt][reg] + bb, 0.0f) * wl;
    }
    int node0b = node0 + wv * 16;
    #pragma unroll
    for (int reg = 0; reg < 4; ++reg) {
        float p = part[reg];
        p += __shfl_xor(p, 1, 64);
        p += __shfl_xor(p, 2, 64);
        p += __shfl_xor(p, 4, 64);
        p += __shfl_xor(p, 8, 64);
        int node = node0b + quad * 4 + reg;
        if (m == 0 && node < N_NODES) snode[node] = p;
    }
}

// ---------------- pooling: out[g] = mean(snode over graph g) + bl ----------------

__global__ __launch_bounds__(256) void k_pool(const float* __restrict__ snode,
                                              const int* __restrict__ batch,
                                              const float* __restrict__ bl,
                                              float* __restrict__ out) {
    int g = blockIdx.x;
    int tid = threadIdx.x;
    __shared__ float sred[4];

    int lo = 0, hi = N_NODES;
    while (lo < hi) { int mid = (lo + hi) >> 1; if (batch[mid] < g) lo = mid + 1; else hi = mid; }
    int start = lo;
    hi = N_NODES;
    while (lo < hi) { int mid = (lo + hi) >> 1; if (batch[mid] < g + 1) lo = mid + 1; else hi = mid; }
    int end = lo;

    float acc = 0.0f;
    for (int n = start + tid; n < end; n += 256) acc += snode[n];

    #pragma unroll
    for (int off = 32; off; off >>= 1) acc += __shfl_down(acc, off, 64);
    int wave = tid >> 6, lane = tid & 63;
    if (lane == 0) sred[wave] = acc;
    __syncthreads();
    if (tid == 0) {
        float s = sred[0] + sred[1] + sred[2] + sred[3];
        float cnt = (float)(end - start);
        out[g] = s / fmaxf(cnt, 1.0f) + bl[0];
    }
}

// ---------------- launch ----------------

extern "C" void kernel_launch(void* const* d_in, const int* in_sizes, int n_in,
                              void* d_out, int out_size, void* d_ws, size_t ws_size,
                              hipStream_t stream) {
    const float* x    = (const float*)d_in[0];
    const int*   src  = (const int*)d_in[1];
    const int*   dst  = src + N_EDGES;
    const int*   batch= (const int*)d_in[2];
    const float* W1   = (const float*)d_in[3];
    const float* b1   = (const float*)d_in[4];
    const float* W2   = (const float*)d_in[5];
    const float* b2   = (const float*)d_in[6];
    const float* Wl   = (const float*)d_in[7];
    const float* bl   = (const float*)d_in[8];
    float* out = (float*)d_out;

    // byte-offset workspace layout, 256 B aligned chunks
    char* w = (char*)d_ws;
    size_t off = 0;
    auto alloc = [&](size_t bytes) { char* p = w + off; off = (off + bytes + 255) & ~(size_t)255; return p; };

    ushort_t* h1   = (ushort_t*)alloc((size_t)(N_NODES + 1) * HIDDEN * 2);   // 25.6 MB (+sentinel)
    int*   ebuf    = (int*)alloc((size_t)NBKT * CAPB * 4);                    // 8.0 MB
    ushort_t* xb   = (ushort_t*)alloc((size_t)(N_NODES + 1) * N_FEAT * 2);   // 3.2 MB (+sentinel)
    float* dinv    = (float*)alloc(N_NODES * 4);
    float* snode   = (float*)alloc(N_NODES * 4);
    int*   cnt     = (int*)alloc(N_NODES * 4);
    int*   esrc64  = (int*)alloc((size_t)N_NODES * CAP * 4);                  // 25.6 MB
    ushort_t* Bp   = (ushort_t*)alloc(16384 * 2);                             // 32 KB
    int*   bcnt    = (int*)alloc(NBKT * 4);

    // build: memset bcnt, partition (+packB tail), per-bucket rank (+prescale+sentinels)
    hipMemsetAsync(bcnt, 0, NBKT * sizeof(int), stream);
    k_part<<<N_EDGES / EPB + 64, 256, 0, stream>>>(src, dst, bcnt, ebuf, W2, Bp);
    k_fill<<<NBKT, 256, 0, stream>>>(bcnt, ebuf, x, esrc64, cnt, dinv, xb, h1);

    // layer 1 fused: wide-row bf16 gather + LDS mm1 -> h1'
    k_agg1f<<<N_NODES / 32, 256, 0, stream>>>(cnt, esrc64, dinv, xb, W1, b1, h1);

    // layer 2 fused: gather aggregate -> LDS -> MFMA mm2 + head dot (2-wave blocks)
    k_l2<<<N_NODES / 32, 128, 0, stream>>>(cnt, esrc64, dinv, h1, Bp, b2, Wl, snode);

    // pool + bias
    k_pool<<<N_GRAPHS, 256, 0, stream>>>(snode, batch, bl, out);
}